// Round 1
// baseline (724.922 us; speedup 1.0000x reference)
//
#include <hip/hip_runtime.h>
#include <hip/hip_bf16.h>
#include <math.h>

// Problem constants (B=2, C=256, H=W=128, N=16384, SR=4, HEADS=8, hd=32, M=1024)
#define EPSF 1e-5f
#define SCALE 0.17677669529663687f  // 1/sqrt(32)

// ---------------------------------------------------------------------------
// k_wqT: transpose w_q (256x256) -> wqT[c][o] so scores kernel stages coalesced
__global__ __launch_bounds__(256) void k_wqT(const float* __restrict__ wq,
                                             float* __restrict__ wqT) {
    int c = blockIdx.x, o = threadIdx.x;
    wqT[c * 256 + o] = wq[o * 256 + c];
}

// ---------------------------------------------------------------------------
// k_mean: v[b,c] = mean_n x[b,c,n].  One block per (b,c).
__global__ __launch_bounds__(256) void k_mean(const float* __restrict__ x,
                                              float* __restrict__ v) {
    __shared__ float wsum[4];
    int t = threadIdx.x, bid = blockIdx.x;
    const float* p = x + (size_t)bid * 16384;
    float s = 0.f;
#pragma unroll
    for (int i = 0; i < 16; ++i) {
        float4 a = *(const float4*)&p[(t + (i << 8)) << 2];
        s += a.x + a.y + a.z + a.w;
    }
#pragma unroll
    for (int off = 32; off; off >>= 1) s += __shfl_down(s, off, 64);
    if ((t & 63) == 0) wsum[t >> 6] = s;
    __syncthreads();
    if (t == 0) v[bid] = (wsum[0] + wsum[1] + wsum[2] + wsum[3]) * (1.0f / 16384.0f);
}

// ---------------------------------------------------------------------------
// k_ab: A[b,o] = (W_proj v)[b,o] * inv[o];  B0[o] = beta[o] - mean[o]*inv[o]
__global__ __launch_bounds__(256) void k_ab(const float* __restrict__ v,
                                            const float* __restrict__ wproj,
                                            const float* __restrict__ pg,
                                            const float* __restrict__ pb,
                                            const float* __restrict__ pm,
                                            const float* __restrict__ pvar,
                                            float* __restrict__ A,
                                            float* __restrict__ B0) {
    __shared__ float vl[256];
    int t = threadIdx.x, b = blockIdx.x;
    vl[t] = v[b * 256 + t];
    __syncthreads();
    const float* wr = wproj + t * 256;
    float s = 0.f;
#pragma unroll 8
    for (int c = 0; c < 256; c += 4) {
        float4 w = *(const float4*)&wr[c];
        s += w.x * vl[c] + w.y * vl[c + 1] + w.z * vl[c + 2] + w.w * vl[c + 3];
    }
    float inv = pg[t] / sqrtf(pvar[t] + EPSF);
    A[b * 256 + t] = s * inv;
    if (b == 0) B0[t] = pb[t] - pm[t] * inv;
}

// ---------------------------------------------------------------------------
// k_conv_part: conv(k=4,s=4) as GEMM  Wsr(256x4096) @ P(4096x1024) per b,
// split-K by 4 -> partials.  Tile 64o x 128m, K-chunk 32.  Grid 256 blocks.
__global__ __launch_bounds__(256) void k_conv_part(const float* __restrict__ x,
                                                   const float* __restrict__ wsr,
                                                   float* __restrict__ xrp) {
    __shared__ __align__(16) float At[32 * 68];   // [k][o] padded
    __shared__ __align__(16) float Bt[32 * 132];  // [k][m] padded
    int t = threadIdx.x, bid = blockIdx.x;
    int ks = bid & 3, mt = (bid >> 2) & 7, ot = (bid >> 5) & 3, b = bid >> 7;
    int og = t & 15, mgq = t >> 4;  // 4 o's, 8 m's per thread
    float acc[4][8];
#pragma unroll
    for (int a = 0; a < 4; ++a)
#pragma unroll
        for (int j = 0; j < 8; ++j) acc[a][j] = 0.f;
    const int kbase = ks << 10;

    for (int kc = 0; kc < 32; ++kc) {
        __syncthreads();
        // stage A (transpose scatter): wsr row-major [o][kappa]
#pragma unroll
        for (int i = 0; i < 2; ++i) {
            int e4 = t + (i << 8);
            int o = e4 >> 3, k4 = (e4 & 7) << 2;
            float4 a = *(const float4*)&wsr[(ot * 64 + o) * 4096 + kbase + (kc << 5) + k4];
            At[(k4 + 0) * 68 + o] = a.x;
            At[(k4 + 1) * 68 + o] = a.y;
            At[(k4 + 2) * 68 + o] = a.z;
            At[(k4 + 3) * 68 + o] = a.w;
        }
        // stage B (patch gather from x)
#pragma unroll
        for (int i = 0; i < 16; ++i) {
            int e = t + (i << 8);
            int k = e >> 7, m = e & 127;
            int kap = kbase + (kc << 5) + k;
            int ci = kap >> 4, p = (kap >> 2) & 3, qq = kap & 3;
            int mgl = (mt << 7) + m;
            int hm = mgl >> 5, wm = mgl & 31;
            Bt[k * 132 + m] =
                x[((b * 256 + ci) << 14) + ((hm << 2) + p) * 128 + (wm << 2) + qq];
        }
        __syncthreads();
#pragma unroll
        for (int k = 0; k < 32; ++k) {
            float4 a4 = *(const float4*)&At[k * 68 + (og << 2)];
            float4 b0 = *(const float4*)&Bt[k * 132 + (mgq << 3)];
            float4 b1 = *(const float4*)&Bt[k * 132 + (mgq << 3) + 4];
            float av[4] = {a4.x, a4.y, a4.z, a4.w};
            float bv[8] = {b0.x, b0.y, b0.z, b0.w, b1.x, b1.y, b1.z, b1.w};
#pragma unroll
            for (int a = 0; a < 4; ++a)
#pragma unroll
                for (int j = 0; j < 8; ++j) acc[a][j] = fmaf(av[a], bv[j], acc[a][j]);
        }
    }
    float* dst = xrp + ((ks * 2 + b) * 262144) + (ot * 64 + (og << 2)) * 1024 +
                 (mt << 7) + (mgq << 3);
#pragma unroll
    for (int a = 0; a < 4; ++a) {
        *(float4*)&dst[a * 1024] = make_float4(acc[a][0], acc[a][1], acc[a][2], acc[a][3]);
        *(float4*)&dst[a * 1024 + 4] = make_float4(acc[a][4], acc[a][5], acc[a][6], acc[a][7]);
    }
}

// ---------------------------------------------------------------------------
// k_conv_comb: xr = BN(sum of 4 partials)
__global__ __launch_bounds__(256) void k_conv_comb(const float* __restrict__ xrp,
                                                   const float* __restrict__ sg,
                                                   const float* __restrict__ sb,
                                                   const float* __restrict__ smn,
                                                   const float* __restrict__ svar,
                                                   float* __restrict__ xr) {
    int idx4 = blockIdx.x * 256 + threadIdx.x;
    int flat = idx4 << 2;
    float4 s0 = *(const float4*)&xrp[flat];
    float4 s1 = *(const float4*)&xrp[524288 + flat];
    float4 s2 = *(const float4*)&xrp[1048576 + flat];
    float4 s3 = *(const float4*)&xrp[1572864 + flat];
    int o = (flat >> 10) & 255;
    float inv = sg[o] / sqrtf(svar[o] + EPSF);
    float mn = smn[o], bt = sb[o];
    float4 r;
    r.x = (s0.x + s1.x + s2.x + s3.x - mn) * inv + bt;
    r.y = (s0.y + s1.y + s2.y + s3.y - mn) * inv + bt;
    r.z = (s0.z + s1.z + s2.z + s3.z - mn) * inv + bt;
    r.w = (s0.w + s1.w + s2.w + s3.w - mn) * inv + bt;
    *(float4*)&xr[flat] = r;
}

// ---------------------------------------------------------------------------
// k_kmat: kk[b,o,m] = SCALE * sum_c wk[o,c] * xr[b,c,m].  Tile 32o x 128m.
__global__ __launch_bounds__(256) void k_kmat(const float* __restrict__ wk,
                                              const float* __restrict__ xr,
                                              float* __restrict__ kk) {
    __shared__ __align__(16) float At[32 * 36];   // [k][o]
    __shared__ __align__(16) float Bt[32 * 132];  // [k][m]
    int t = threadIdx.x, bid = blockIdx.x;
    int mt = bid & 7, ot = (bid >> 3) & 7, b = bid >> 6;
    int og = t & 7, mg = t >> 3;  // 4 o's, 4 m's
    float acc[4][4];
#pragma unroll
    for (int a = 0; a < 4; ++a)
#pragma unroll
        for (int j = 0; j < 4; ++j) acc[a][j] = 0.f;

    for (int kc = 0; kc < 8; ++kc) {
        __syncthreads();
        {
            int o = t >> 3, k4 = (t & 7) << 2;
            float4 a = *(const float4*)&wk[(ot * 32 + o) * 256 + (kc << 5) + k4];
            At[(k4 + 0) * 36 + o] = a.x * SCALE;
            At[(k4 + 1) * 36 + o] = a.y * SCALE;
            At[(k4 + 2) * 36 + o] = a.z * SCALE;
            At[(k4 + 3) * 36 + o] = a.w * SCALE;
        }
#pragma unroll
        for (int i = 0; i < 4; ++i) {
            int e4 = t + (i << 8);
            int k = e4 >> 5, m4 = (e4 & 31) << 2;
            *(float4*)&Bt[k * 132 + m4] =
                *(const float4*)&xr[(b * 256 + (kc << 5) + k) * 1024 + (mt << 7) + m4];
        }
        __syncthreads();
#pragma unroll
        for (int k = 0; k < 32; ++k) {
            float4 a4 = *(const float4*)&At[k * 36 + (og << 2)];
            float4 b4 = *(const float4*)&Bt[k * 132 + (mg << 2)];
            float av[4] = {a4.x, a4.y, a4.z, a4.w};
            float bv[4] = {b4.x, b4.y, b4.z, b4.w};
#pragma unroll
            for (int a = 0; a < 4; ++a)
#pragma unroll
                for (int j = 0; j < 4; ++j) acc[a][j] = fmaf(av[a], bv[j], acc[a][j]);
        }
    }
    float* dst = kk + (b * 256 + ot * 32 + (og << 2)) * 1024 + (mt << 7) + (mg << 2);
#pragma unroll
    for (int a = 0; a < 4; ++a)
        *(float4*)&dst[a * 1024] = make_float4(acc[a][0], acc[a][1], acc[a][2], acc[a][3]);
}

// ---------------------------------------------------------------------------
// k_scores: fused q-compute + scores-max + head-sum + rank-1 epilogue.
// Block = 256 thr, handles (b, 128 n's).  Grid = 256.
#define SM_XT 0       // 64*128 (q phase)
#define SM_WT 8192    // 64*32  (q phase)
#define SM_KT 0       // 32*260 (m phase)
#define SM_RED 8704   // 8*128  (m phase)
#define SM_AT 0       // 256 (epilogue)
#define SM_B0T 256    // 256 (epilogue)
#define SM_QT 10240   // 128*36
#define SM_ST 14848   // 128
#define SM_TOT 14976

__global__ __launch_bounds__(256) void k_scores(const float* __restrict__ x,
                                                const float* __restrict__ wqT,
                                                const float* __restrict__ kk,
                                                const float* __restrict__ A,
                                                const float* __restrict__ B0,
                                                float* __restrict__ out) {
    __shared__ __align__(16) float sm[SM_TOT];
    const int t = threadIdx.x;
    const int bx = blockIdx.x;
    const int b = bx >> 7;
    const int n0 = (bx & 127) << 7;
    if (t < 128) sm[SM_ST + t] = 0.f;
    const int na = (t & 63) << 1;  // q phase: 2 n's
    const int d0 = (t >> 6) << 3;  // q phase: 8 d's
    const int nq = t & 31;         // m phase: 4 n's (nq + 32*i)
    const int mg = t >> 5;         // m phase: 8-way m split

    for (int h = 0; h < 8; ++h) {
        // ---------------- q phase: q[n][d] for this head ----------------
        float qa0[8], qa1[8];
#pragma unroll
        for (int j = 0; j < 8; ++j) { qa0[j] = 0.f; qa1[j] = 0.f; }
        for (int cc = 0; cc < 4; ++cc) {
            const int c0 = cc << 6;
            __syncthreads();
            {
                const float* src = x + ((b * 256 + c0) << 14) + n0;
#pragma unroll
                for (int i = 0; i < 8; ++i) {
                    int e4 = t + (i << 8);
                    int c = e4 >> 5, n4 = (e4 & 31) << 2;
                    *(float4*)&sm[SM_XT + c * 128 + n4] =
                        *(const float4*)&src[(c << 14) + n4];
                }
                const float* srcw = wqT + c0 * 256 + (h << 5);
#pragma unroll
                for (int i = 0; i < 2; ++i) {
                    int e4 = t + (i << 8);
                    int c = e4 >> 3, d4 = (e4 & 7) << 2;
                    *(float4*)&sm[SM_WT + (c << 5) + d4] =
                        *(const float4*)&srcw[c * 256 + d4];
                }
            }
            __syncthreads();
#pragma unroll 4
            for (int c = 0; c < 64; ++c) {
                float2 xv = *(const float2*)&sm[SM_XT + c * 128 + na];
                float4 w0 = *(const float4*)&sm[SM_WT + (c << 5) + d0];
                float4 w1 = *(const float4*)&sm[SM_WT + (c << 5) + d0 + 4];
                float wv[8] = {w0.x, w0.y, w0.z, w0.w, w1.x, w1.y, w1.z, w1.w};
#pragma unroll
                for (int j = 0; j < 8; ++j) {
                    qa0[j] = fmaf(wv[j], xv.x, qa0[j]);
                    qa1[j] = fmaf(wv[j], xv.y, qa1[j]);
                }
            }
        }
        *(float4*)&sm[SM_QT + na * 36 + d0] = make_float4(qa0[0], qa0[1], qa0[2], qa0[3]);
        *(float4*)&sm[SM_QT + na * 36 + d0 + 4] = make_float4(qa0[4], qa0[5], qa0[6], qa0[7]);
        *(float4*)&sm[SM_QT + (na + 1) * 36 + d0] = make_float4(qa1[0], qa1[1], qa1[2], qa1[3]);
        *(float4*)&sm[SM_QT + (na + 1) * 36 + d0 + 4] = make_float4(qa1[4], qa1[5], qa1[6], qa1[7]);
        __syncthreads();
        // load q fragments for the m phase (4 n's x 32 d in VGPRs)
        float qr0[32], qr1[32], qr2[32], qr3[32];
#pragma unroll
        for (int d4 = 0; d4 < 8; ++d4) {
            float4 q0 = *(const float4*)&sm[SM_QT + (nq) * 36 + (d4 << 2)];
            float4 q1 = *(const float4*)&sm[SM_QT + (nq + 32) * 36 + (d4 << 2)];
            float4 q2 = *(const float4*)&sm[SM_QT + (nq + 64) * 36 + (d4 << 2)];
            float4 q3 = *(const float4*)&sm[SM_QT + (nq + 96) * 36 + (d4 << 2)];
            qr0[(d4 << 2) + 0] = q0.x; qr0[(d4 << 2) + 1] = q0.y;
            qr0[(d4 << 2) + 2] = q0.z; qr0[(d4 << 2) + 3] = q0.w;
            qr1[(d4 << 2) + 0] = q1.x; qr1[(d4 << 2) + 1] = q1.y;
            qr1[(d4 << 2) + 2] = q1.z; qr1[(d4 << 2) + 3] = q1.w;
            qr2[(d4 << 2) + 0] = q2.x; qr2[(d4 << 2) + 1] = q2.y;
            qr2[(d4 << 2) + 2] = q2.z; qr2[(d4 << 2) + 3] = q2.w;
            qr3[(d4 << 2) + 0] = q3.x; qr3[(d4 << 2) + 1] = q3.y;
            qr3[(d4 << 2) + 2] = q3.z; qr3[(d4 << 2) + 3] = q3.w;
        }
        float mx0 = -INFINITY, mx1 = -INFINITY, mx2 = -INFINITY, mx3 = -INFINITY;
        const float* kkb = kk + ((b * 256 + (h << 5)) << 10);
        // ---------------- m phase: max over 1024 kv positions ----------------
        for (int mc = 0; mc < 4; ++mc) {
            __syncthreads();
#pragma unroll
            for (int i = 0; i < 8; ++i) {
                int e4 = t + (i << 8);
                int d = e4 >> 6, m4 = (e4 & 63) << 2;
                *(float4*)&sm[SM_KT + d * 260 + m4] =
                    *(const float4*)&kkb[(d << 10) + (mc << 8) + m4];
            }
            __syncthreads();
#pragma unroll 2
            for (int mm = 0; mm < 32; ++mm) {
                const int ml = (mg << 5) + mm;
                float s0 = 0.f, s1 = 0.f, s2 = 0.f, s3 = 0.f;
#pragma unroll
                for (int d = 0; d < 32; ++d) {
                    float kv = sm[SM_KT + d * 260 + ml];
                    s0 = fmaf(qr0[d], kv, s0);
                    s1 = fmaf(qr1[d], kv, s1);
                    s2 = fmaf(qr2[d], kv, s2);
                    s3 = fmaf(qr3[d], kv, s3);
                }
                mx0 = fmaxf(mx0, s0); mx1 = fmaxf(mx1, s1);
                mx2 = fmaxf(mx2, s2); mx3 = fmaxf(mx3, s3);
            }
        }
        sm[SM_RED + (mg << 7) + nq] = mx0;
        sm[SM_RED + (mg << 7) + nq + 32] = mx1;
        sm[SM_RED + (mg << 7) + nq + 64] = mx2;
        sm[SM_RED + (mg << 7) + nq + 96] = mx3;
        __syncthreads();
        if (t < 128) {
            float v = sm[SM_RED + t];
#pragma unroll
            for (int g = 1; g < 8; ++g) v = fmaxf(v, sm[SM_RED + (g << 7) + t]);
            sm[SM_ST + t] += v;  // head sum
        }
        // next head's leading __syncthreads() protects smem reuse
    }
    __syncthreads();
    sm[SM_AT + t] = A[b * 256 + t];
    sm[SM_B0T + t] = B0[t];
    __syncthreads();
    float* outb = out + ((size_t)b << 22) + n0;
#pragma unroll
    for (int i = 0; i < 32; ++i) {
        int e4 = t + (i << 8);
        int c = e4 >> 5, n4 = (e4 & 31) << 2;
        float4 s4 = *(const float4*)&sm[SM_ST + n4];
        float a = sm[SM_AT + c], bv = sm[SM_B0T + c];
        float4 o4 = make_float4(fmaf(a, s4.x, bv), fmaf(a, s4.y, bv),
                                fmaf(a, s4.z, bv), fmaf(a, s4.w, bv));
        *(float4*)&outb[(c << 14) + n4] = o4;
    }
}

// ---------------------------------------------------------------------------
extern "C" void kernel_launch(void* const* d_in, const int* in_sizes, int n_in,
                              void* d_out, int out_size, void* d_ws, size_t ws_size,
                              hipStream_t stream) {
    const float* x    = (const float*)d_in[0];
    const float* wq   = (const float*)d_in[1];
    const float* wk   = (const float*)d_in[2];
    const float* wsr  = (const float*)d_in[3];
    const float* sg   = (const float*)d_in[4];
    const float* sb   = (const float*)d_in[5];
    const float* smn  = (const float*)d_in[6];
    const float* svr  = (const float*)d_in[7];
    const float* wproj= (const float*)d_in[8];
    const float* pg   = (const float*)d_in[9];
    const float* pb   = (const float*)d_in[10];
    const float* pm   = (const float*)d_in[11];
    const float* pvr  = (const float*)d_in[12];
    float* out = (float*)d_out;

    // workspace carve (floats): total 3,213,312 floats = 12.3 MB
    float* ws    = (float*)d_ws;
    float* w_v   = ws;                  // 512
    float* w_A   = ws + 512;            // 512
    float* w_B0  = ws + 1024;           // 256
    float* w_wqT = ws + 2048;           // 65536
    float* w_xr  = ws + 67584;          // 524288
    float* w_kk  = ws + 591872;         // 524288
    float* w_xrp = ws + 1116160;        // 2097152

    k_wqT<<<256, 256, 0, stream>>>(wq, w_wqT);
    k_mean<<<512, 256, 0, stream>>>(x, w_v);
    k_ab<<<2, 256, 0, stream>>>(w_v, wproj, pg, pb, pm, pvr, w_A, w_B0);
    k_conv_part<<<256, 256, 0, stream>>>(x, wsr, w_xrp);
    k_conv_comb<<<512, 256, 0, stream>>>(w_xrp, sg, sb, smn, svr, w_xr);
    k_kmat<<<128, 256, 0, stream>>>(wk, w_xr, w_kk);
    k_scores<<<256, 256, 0, stream>>>(x, w_wqT, w_kk, w_A, w_B0, out);
}

// Round 2
// 310.115 us; speedup vs baseline: 2.3376x; 2.3376x over previous
//
#include <hip/hip_runtime.h>
#include <hip/hip_bf16.h>
#include <math.h>

// Problem constants (B=2, C=256, H=W=128, N=16384, SR=4, HEADS=8, hd=32, M=1024)
#define EPSF 1e-5f
#define SCALE 0.17677669529663687f  // 1/sqrt(32)

typedef __bf16 bf16x8 __attribute__((ext_vector_type(8)));
typedef __bf16 bf16x4 __attribute__((ext_vector_type(4)));
typedef float f32x4 __attribute__((ext_vector_type(4)));

// ---------------------------------------------------------------------------
// k_mean: v[b,c] = mean_n x[b,c,n].  One block per (b,c).
__global__ __launch_bounds__(256) void k_mean(const float* __restrict__ x,
                                              float* __restrict__ v) {
    __shared__ float wsum[4];
    int t = threadIdx.x, bid = blockIdx.x;
    const float* p = x + (size_t)bid * 16384;
    float s = 0.f;
#pragma unroll
    for (int i = 0; i < 16; ++i) {
        float4 a = *(const float4*)&p[(t + (i << 8)) << 2];
        s += a.x + a.y + a.z + a.w;
    }
#pragma unroll
    for (int off = 32; off; off >>= 1) s += __shfl_down(s, off, 64);
    if ((t & 63) == 0) wsum[t >> 6] = s;
    __syncthreads();
    if (t == 0) v[bid] = (wsum[0] + wsum[1] + wsum[2] + wsum[3]) * (1.0f / 16384.0f);
}

// ---------------------------------------------------------------------------
// k_ab: A[b,o] = (W_proj v)[b,o] * inv[o];  B0[o] = beta[o] - mean[o]*inv[o]
__global__ __launch_bounds__(256) void k_ab(const float* __restrict__ v,
                                            const float* __restrict__ wproj,
                                            const float* __restrict__ pg,
                                            const float* __restrict__ pb,
                                            const float* __restrict__ pm,
                                            const float* __restrict__ pvar,
                                            float* __restrict__ A,
                                            float* __restrict__ B0) {
    __shared__ float vl[256];
    int t = threadIdx.x, b = blockIdx.x;
    vl[t] = v[b * 256 + t];
    __syncthreads();
    const float* wr = wproj + t * 256;
    float s = 0.f;
#pragma unroll 8
    for (int c = 0; c < 256; c += 4) {
        float4 w = *(const float4*)&wr[c];
        s += w.x * vl[c] + w.y * vl[c + 1] + w.z * vl[c + 2] + w.w * vl[c + 3];
    }
    float inv = pg[t] / sqrtf(pvar[t] + EPSF);
    A[b * 256 + t] = s * inv;
    if (b == 0) B0[t] = pb[t] - pm[t] * inv;
}

// ---------------------------------------------------------------------------
// k_conv_part: conv(k=4,s=4) as GEMM, split-K by 4 -> partials.  (fp32, unchanged)
__global__ __launch_bounds__(256) void k_conv_part(const float* __restrict__ x,
                                                   const float* __restrict__ wsr,
                                                   float* __restrict__ xrp) {
    __shared__ __align__(16) float At[32 * 68];   // [k][o] padded
    __shared__ __align__(16) float Bt[32 * 132];  // [k][m] padded
    int t = threadIdx.x, bid = blockIdx.x;
    int ks = bid & 3, mt = (bid >> 2) & 7, ot = (bid >> 5) & 3, b = bid >> 7;
    int og = t & 15, mgq = t >> 4;  // 4 o's, 8 m's per thread
    float acc[4][8];
#pragma unroll
    for (int a = 0; a < 4; ++a)
#pragma unroll
        for (int j = 0; j < 8; ++j) acc[a][j] = 0.f;
    const int kbase = ks << 10;

    for (int kc = 0; kc < 32; ++kc) {
        __syncthreads();
#pragma unroll
        for (int i = 0; i < 2; ++i) {
            int e4 = t + (i << 8);
            int o = e4 >> 3, k4 = (e4 & 7) << 2;
            float4 a = *(const float4*)&wsr[(ot * 64 + o) * 4096 + kbase + (kc << 5) + k4];
            At[(k4 + 0) * 68 + o] = a.x;
            At[(k4 + 1) * 68 + o] = a.y;
            At[(k4 + 2) * 68 + o] = a.z;
            At[(k4 + 3) * 68 + o] = a.w;
        }
#pragma unroll
        for (int i = 0; i < 16; ++i) {
            int e = t + (i << 8);
            int k = e >> 7, m = e & 127;
            int kap = kbase + (kc << 5) + k;
            int ci = kap >> 4, p = (kap >> 2) & 3, qq = kap & 3;
            int mgl = (mt << 7) + m;
            int hm = mgl >> 5, wm = mgl & 31;
            Bt[k * 132 + m] =
                x[((b * 256 + ci) << 14) + ((hm << 2) + p) * 128 + (wm << 2) + qq];
        }
        __syncthreads();
#pragma unroll
        for (int k = 0; k < 32; ++k) {
            float4 a4 = *(const float4*)&At[k * 68 + (og << 2)];
            float4 b0 = *(const float4*)&Bt[k * 132 + (mgq << 3)];
            float4 b1 = *(const float4*)&Bt[k * 132 + (mgq << 3) + 4];
            float av[4] = {a4.x, a4.y, a4.z, a4.w};
            float bv[8] = {b0.x, b0.y, b0.z, b0.w, b1.x, b1.y, b1.z, b1.w};
#pragma unroll
            for (int a = 0; a < 4; ++a)
#pragma unroll
                for (int j = 0; j < 8; ++j) acc[a][j] = fmaf(av[a], bv[j], acc[a][j]);
        }
    }
    float* dst = xrp + ((ks * 2 + b) * 262144) + (ot * 64 + (og << 2)) * 1024 +
                 (mt << 7) + (mgq << 3);
#pragma unroll
    for (int a = 0; a < 4; ++a) {
        *(float4*)&dst[a * 1024] = make_float4(acc[a][0], acc[a][1], acc[a][2], acc[a][3]);
        *(float4*)&dst[a * 1024 + 4] = make_float4(acc[a][4], acc[a][5], acc[a][6], acc[a][7]);
    }
}

// ---------------------------------------------------------------------------
// k_conv_comb: xr = BN(sum of 4 partials)
__global__ __launch_bounds__(256) void k_conv_comb(const float* __restrict__ xrp,
                                                   const float* __restrict__ sg,
                                                   const float* __restrict__ sb,
                                                   const float* __restrict__ smn,
                                                   const float* __restrict__ svar,
                                                   float* __restrict__ xr) {
    int idx4 = blockIdx.x * 256 + threadIdx.x;
    int flat = idx4 << 2;
    float4 s0 = *(const float4*)&xrp[flat];
    float4 s1 = *(const float4*)&xrp[524288 + flat];
    float4 s2 = *(const float4*)&xrp[1048576 + flat];
    float4 s3 = *(const float4*)&xrp[1572864 + flat];
    int o = (flat >> 10) & 255;
    float inv = sg[o] / sqrtf(svar[o] + EPSF);
    float mn = smn[o], bt = sb[o];
    float4 r;
    r.x = (s0.x + s1.x + s2.x + s3.x - mn) * inv + bt;
    r.y = (s0.y + s1.y + s2.y + s3.y - mn) * inv + bt;
    r.z = (s0.z + s1.z + s2.z + s3.z - mn) * inv + bt;
    r.w = (s0.w + s1.w + s2.w + s3.w - mn) * inv + bt;
    *(float4*)&xr[flat] = r;
}

// ---------------------------------------------------------------------------
// k_kmat: kk[b,o,m] = SCALE * sum_c wk[o,c] * xr[b,c,m].  (fp32, unchanged)
__global__ __launch_bounds__(256) void k_kmat(const float* __restrict__ wk,
                                              const float* __restrict__ xr,
                                              float* __restrict__ kk) {
    __shared__ __align__(16) float At[32 * 36];
    __shared__ __align__(16) float Bt[32 * 132];
    int t = threadIdx.x, bid = blockIdx.x;
    int mt = bid & 7, ot = (bid >> 3) & 7, b = bid >> 6;
    int og = t & 7, mg = t >> 3;
    float acc[4][4];
#pragma unroll
    for (int a = 0; a < 4; ++a)
#pragma unroll
        for (int j = 0; j < 4; ++j) acc[a][j] = 0.f;

    for (int kc = 0; kc < 8; ++kc) {
        __syncthreads();
        {
            int o = t >> 3, k4 = (t & 7) << 2;
            float4 a = *(const float4*)&wk[(ot * 32 + o) * 256 + (kc << 5) + k4];
            At[(k4 + 0) * 36 + o] = a.x * SCALE;
            At[(k4 + 1) * 36 + o] = a.y * SCALE;
            At[(k4 + 2) * 36 + o] = a.z * SCALE;
            At[(k4 + 3) * 36 + o] = a.w * SCALE;
        }
#pragma unroll
        for (int i = 0; i < 4; ++i) {
            int e4 = t + (i << 8);
            int k = e4 >> 5, m4 = (e4 & 31) << 2;
            *(float4*)&Bt[k * 132 + m4] =
                *(const float4*)&xr[(b * 256 + (kc << 5) + k) * 1024 + (mt << 7) + m4];
        }
        __syncthreads();
#pragma unroll
        for (int k = 0; k < 32; ++k) {
            float4 a4 = *(const float4*)&At[k * 36 + (og << 2)];
            float4 b4 = *(const float4*)&Bt[k * 132 + (mg << 2)];
            float av[4] = {a4.x, a4.y, a4.z, a4.w};
            float bv[4] = {b4.x, b4.y, b4.z, b4.w};
#pragma unroll
            for (int a = 0; a < 4; ++a)
#pragma unroll
                for (int j = 0; j < 4; ++j) acc[a][j] = fmaf(av[a], bv[j], acc[a][j]);
        }
    }
    float* dst = kk + (b * 256 + ot * 32 + (og << 2)) * 1024 + (mt << 7) + (mg << 2);
#pragma unroll
    for (int a = 0; a < 4; ++a)
        *(float4*)&dst[a * 1024] = make_float4(acc[a][0], acc[a][1], acc[a][2], acc[a][3]);
}

// ---------------------------------------------------------------------------
// k_kpack: kk fp32 [b][o=h*32+d][m] -> kkb bf16 [b][h][m][d32]  (B-frag layout)
__global__ __launch_bounds__(256) void k_kpack(const float* __restrict__ kk,
                                               __bf16* __restrict__ kkb) {
    int t = threadIdx.x, bid = blockIdx.x;  // bid = b*8+h
    int b = bid >> 3, h = bid & 7;
    const float* src = kk + (b * 256 + h * 32) * 1024;
    __bf16* dst = kkb + bid * 32768;
#pragma unroll 4
    for (int d = 0; d < 32; ++d) {
        float4 vv = *(const float4*)&src[d * 1024 + (t << 2)];
        dst[((t << 2) + 0) * 32 + d] = (__bf16)vv.x;
        dst[((t << 2) + 1) * 32 + d] = (__bf16)vv.y;
        dst[((t << 2) + 2) * 32 + d] = (__bf16)vv.z;
        dst[((t << 2) + 3) * 32 + d] = (__bf16)vv.w;
    }
}

// ---------------------------------------------------------------------------
// k_wqbf: wq fp32 [o][c] -> bf16 same layout (B-frag rows for q-GEMM)
__global__ __launch_bounds__(256) void k_wqbf(const float* __restrict__ wq,
                                              __bf16* __restrict__ wqb) {
    int e = blockIdx.x * 256 + threadIdx.x;  // 64 blocks, 4 elems each
    float4 vv = *(const float4*)&wq[e << 2];
    bf16x4 p;
    p[0] = (__bf16)vv.x; p[1] = (__bf16)vv.y; p[2] = (__bf16)vv.z; p[3] = (__bf16)vv.w;
    *(bf16x4*)&wqb[e << 2] = p;
}

// ---------------------------------------------------------------------------
// k_xt: x fp32 [b][c][n] -> xT bf16 [b][n][c]  (LDS-tiled transpose)
__global__ __launch_bounds__(256) void k_xt(const float* __restrict__ x,
                                            __bf16* __restrict__ xT) {
    __shared__ float ts[32 * 132];
    int t = threadIdx.x, bid = blockIdx.x;
    int b = bid >> 7, n0 = (bid & 127) << 7;
    for (int s8 = 0; s8 < 8; ++s8) {
        int c0 = s8 << 5;
        __syncthreads();
#pragma unroll
        for (int i = 0; i < 4; ++i) {
            int e = t + (i << 8);
            int c = e >> 5, n4 = (e & 31) << 2;
            *(float4*)&ts[c * 132 + n4] =
                *(const float4*)&x[((size_t)(b * 256 + c0 + c) << 14) + n0 + n4];
        }
        __syncthreads();
        int n = t >> 1, ch = (t & 1) << 4;
        bf16x8 p0, p1;
#pragma unroll
        for (int j = 0; j < 8; ++j) p0[j] = (__bf16)ts[(ch + j) * 132 + n];
#pragma unroll
        for (int j = 0; j < 8; ++j) p1[j] = (__bf16)ts[(ch + 8 + j) * 132 + n];
        __bf16* dst = xT + ((size_t)(b * 16384 + n0 + n) << 8) + c0 + ch;
        *(bf16x8*)dst = p0;
        *(bf16x8*)(dst + 8) = p1;
    }
}

// ---------------------------------------------------------------------------
// k_scores2: fused MFMA q-GEMM + MFMA scores + max + head-sum + rank-1 epilogue.
// Block: 256 thr (4 waves), n-range 64.  Waves: o-split in q phase, m-split in
// score phase.  Grid = 2 b * 256 nchunks = 512.
__global__ __launch_bounds__(256) void k_scores2(const __bf16* __restrict__ xT,
                                                 const __bf16* __restrict__ wqb,
                                                 const __bf16* __restrict__ kkb,
                                                 const float* __restrict__ A,
                                                 const float* __restrict__ B0,
                                                 float* __restrict__ out) {
    __shared__ __align__(16) __bf16 qs[64 * 264];  // q tile [n_local][o=h*32+d], pad 264
    __shared__ float smax[256];                    // per-wave per-n maxes
    __shared__ float ss[64];                       // head-sum accumulator
    __shared__ float sA[256], sB[256];
    const int t = threadIdx.x;
    const int w = t >> 6;          // wave id
    const int lane = t & 63;
    const int ln = lane & 15;
    const int quad = lane >> 4;
    const int b = blockIdx.x >> 8;
    const int n0 = (blockIdx.x & 255) << 6;
    if (t < 64) ss[t] = 0.f;

    // ---------------- q phase: q[n0..n0+63][o = w*64 .. w*64+63] ----------------
    f32x4 acc[4][4];
#pragma unroll
    for (int nt = 0; nt < 4; ++nt)
#pragma unroll
        for (int ot = 0; ot < 4; ++ot) acc[nt][ot] = (f32x4){0.f, 0.f, 0.f, 0.f};

    for (int cc = 0; cc < 8; ++cc) {
        const int cb = (cc << 5) + (quad << 3);
        bf16x8 af[4], bf[4];
#pragma unroll
        for (int nt = 0; nt < 4; ++nt)
            af[nt] = *(const bf16x8*)&xT[((size_t)(b * 16384 + n0 + (nt << 4) + ln) << 8) + cb];
#pragma unroll
        for (int ot = 0; ot < 4; ++ot)
            bf[ot] = *(const bf16x8*)&wqb[(((w << 6) + (ot << 4) + ln) << 8) + cb];
#pragma unroll
        for (int nt = 0; nt < 4; ++nt)
#pragma unroll
            for (int ot = 0; ot < 4; ++ot)
                acc[nt][ot] = __builtin_amdgcn_mfma_f32_16x16x32_bf16(af[nt], bf[ot],
                                                                      acc[nt][ot], 0, 0, 0);
    }
    // D -> LDS (bf16), layout [n_local][o]:  row = quad*4+reg, col = ln
#pragma unroll
    for (int nt = 0; nt < 4; ++nt)
#pragma unroll
        for (int ot = 0; ot < 4; ++ot)
#pragma unroll
            for (int r = 0; r < 4; ++r)
                qs[((nt << 4) + (quad << 2) + r) * 264 + (w << 6) + (ot << 4) + ln] =
                    (__bf16)acc[nt][ot][r];
    __syncthreads();

    // ---------------- score phase: per head, max over this wave's 16 m-tiles ----
    const f32x4 zf = {0.f, 0.f, 0.f, 0.f};
    for (int h = 0; h < 8; ++h) {
        bf16x8 qa[4];
#pragma unroll
        for (int nt = 0; nt < 4; ++nt)
            qa[nt] = *(const bf16x8*)&qs[((nt << 4) + ln) * 264 + (h << 5) + (quad << 3)];
        f32x4 mx[4];
#pragma unroll
        for (int nt = 0; nt < 4; ++nt) mx[nt] = (f32x4){-INFINITY, -INFINITY, -INFINITY, -INFINITY};
        const __bf16* kb_base = kkb + (((size_t)(b * 8 + h) << 10) << 5);
#pragma unroll 2
        for (int i = 0; i < 16; ++i) {
            const int m = ((w << 4) + i) << 4;  // m-tile base
            bf16x8 kb = *(const bf16x8*)&kb_base[((m + ln) << 5) + (quad << 3)];
#pragma unroll
            for (int nt = 0; nt < 4; ++nt) {
                f32x4 d = __builtin_amdgcn_mfma_f32_16x16x32_bf16(qa[nt], kb, zf, 0, 0, 0);
                mx[nt][0] = fmaxf(mx[nt][0], d[0]);
                mx[nt][1] = fmaxf(mx[nt][1], d[1]);
                mx[nt][2] = fmaxf(mx[nt][2], d[2]);
                mx[nt][3] = fmaxf(mx[nt][3], d[3]);
            }
        }
        // cross-lane max within 16-lane groups (m dimension)
#pragma unroll
        for (int nt = 0; nt < 4; ++nt) {
#pragma unroll
            for (int st = 1; st < 16; st <<= 1) {
                mx[nt][0] = fmaxf(mx[nt][0], __shfl_xor(mx[nt][0], st, 64));
                mx[nt][1] = fmaxf(mx[nt][1], __shfl_xor(mx[nt][1], st, 64));
                mx[nt][2] = fmaxf(mx[nt][2], __shfl_xor(mx[nt][2], st, 64));
                mx[nt][3] = fmaxf(mx[nt][3], __shfl_xor(mx[nt][3], st, 64));
            }
        }
        if (ln == 0) {
#pragma unroll
            for (int nt = 0; nt < 4; ++nt)
#pragma unroll
                for (int r = 0; r < 4; ++r)
                    smax[(w << 6) + (nt << 4) + (quad << 2) + r] = mx[nt][r];
        }
        __syncthreads();
        if (t < 64) {
            float vv = fmaxf(fmaxf(smax[t], smax[64 + t]), fmaxf(smax[128 + t], smax[192 + t]));
            ss[t] += vv;
        }
        __syncthreads();
    }

    // ---------------- epilogue: out[b][c][n0..n0+63] = A[b][c]*s[n] + B0[c] ----
    sA[t] = A[b * 256 + t];
    sB[t] = B0[t];
    __syncthreads();
#pragma unroll
    for (int i = 0; i < 16; ++i) {
        int e = t + (i << 8);
        int c = e >> 4, n4 = (e & 15) << 2;
        float4 s4 = *(const float4*)&ss[n4];
        float a = sA[c], bb = sB[c];
        float4 o4 = make_float4(fmaf(a, s4.x, bb), fmaf(a, s4.y, bb),
                                fmaf(a, s4.z, bb), fmaf(a, s4.w, bb));
        *(float4*)&out[((size_t)(b * 256 + c) << 14) + n0 + n4] = o4;
    }
}

// ---------------------------------------------------------------------------
extern "C" void kernel_launch(void* const* d_in, const int* in_sizes, int n_in,
                              void* d_out, int out_size, void* d_ws, size_t ws_size,
                              hipStream_t stream) {
    const float* x    = (const float*)d_in[0];
    const float* wq   = (const float*)d_in[1];
    const float* wk   = (const float*)d_in[2];
    const float* wsr  = (const float*)d_in[3];
    const float* sg   = (const float*)d_in[4];
    const float* sb   = (const float*)d_in[5];
    const float* smn  = (const float*)d_in[6];
    const float* svr  = (const float*)d_in[7];
    const float* wproj= (const float*)d_in[8];
    const float* pg   = (const float*)d_in[9];
    const float* pb   = (const float*)d_in[10];
    const float* pm   = (const float*)d_in[11];
    const float* pvr  = (const float*)d_in[12];
    float* out = (float*)d_out;

    // workspace carve (bytes), total ~19.2 MB.  xT aliases kk+xrp (dead by then).
    char* W = (char*)d_ws;
    float*  w_v   = (float*) (W + 0);         // 512 f
    float*  w_A   = (float*) (W + 4096);      // 512 f
    float*  w_B0  = (float*) (W + 8192);      // 256 f
    __bf16* w_wqb = (__bf16*)(W + 16384);     // 65536 bf16 (128 KB)
    float*  w_xr  = (float*) (W + 147456);    // 524288 f (2 MB)
    __bf16* w_kkb = (__bf16*)(W + 2244608);   // 524288 bf16 (1 MB)
    float*  w_kk  = (float*) (W + 3293184);   // 524288 f (2 MB)
    float*  w_xrp = (float*) (W + 5390336);   // 2097152 f (8 MB)
    __bf16* w_xT  = (__bf16*)(W + 3293184);   // 8388608 bf16 (16 MB) — alias

    k_mean<<<512, 256, 0, stream>>>(x, w_v);
    k_ab<<<2, 256, 0, stream>>>(w_v, wproj, pg, pb, pm, pvr, w_A, w_B0);
    k_conv_part<<<256, 256, 0, stream>>>(x, wsr, w_xrp);
    k_conv_comb<<<512, 256, 0, stream>>>(w_xrp, sg, sb, smn, svr, w_xr);
    k_kmat<<<128, 256, 0, stream>>>(wk, w_xr, w_kk);
    k_kpack<<<16, 256, 0, stream>>>(w_kk, w_kkb);
    k_wqbf<<<64, 256, 0, stream>>>(wq, w_wqb);
    k_xt<<<256, 256, 0, stream>>>(x, w_xT);   // clobbers w_kk / w_xrp (both dead)
    k_scores2<<<512, 256, 0, stream>>>(w_xT, w_wqb, w_kkb, w_A, w_B0, out);
}

// Round 3
// 247.080 us; speedup vs baseline: 2.9340x; 1.2551x over previous
//
#include <hip/hip_runtime.h>
#include <hip/hip_bf16.h>
#include <math.h>

// Problem constants (B=2, C=256, H=W=128, N=16384, SR=4, HEADS=8, hd=32, M=1024)
#define EPSF 1e-5f
#define SCALE 0.17677669529663687f  // 1/sqrt(32)

typedef __bf16 bf16x8 __attribute__((ext_vector_type(8)));
typedef __bf16 bf16x4 __attribute__((ext_vector_type(4)));
typedef float f32x4 __attribute__((ext_vector_type(4)));

// ---------------------------------------------------------------------------
// k_mean: v[b,c] = mean_n x[b,c,n].  One block per (b,c).
__global__ __launch_bounds__(256) void k_mean(const float* __restrict__ x,
                                              float* __restrict__ v) {
    __shared__ float wsum[4];
    int t = threadIdx.x, bid = blockIdx.x;
    const float* p = x + (size_t)bid * 16384;
    float s = 0.f;
#pragma unroll
    for (int i = 0; i < 16; ++i) {
        float4 a = *(const float4*)&p[(t + (i << 8)) << 2];
        s += a.x + a.y + a.z + a.w;
    }
#pragma unroll
    for (int off = 32; off; off >>= 1) s += __shfl_down(s, off, 64);
    if ((t & 63) == 0) wsum[t >> 6] = s;
    __syncthreads();
    if (t == 0) v[bid] = (wsum[0] + wsum[1] + wsum[2] + wsum[3]) * (1.0f / 16384.0f);
}

// ---------------------------------------------------------------------------
// k_ab: A[b,o] = (W_proj v)[b,o] * inv[o];  B0[o] = beta[o] - mean[o]*inv[o]
__global__ __launch_bounds__(256) void k_ab(const float* __restrict__ v,
                                            const float* __restrict__ wproj,
                                            const float* __restrict__ pg,
                                            const float* __restrict__ pb,
                                            const float* __restrict__ pm,
                                            const float* __restrict__ pvar,
                                            float* __restrict__ A,
                                            float* __restrict__ B0) {
    __shared__ float vl[256];
    int t = threadIdx.x, b = blockIdx.x;
    vl[t] = v[b * 256 + t];
    __syncthreads();
    const float* wr = wproj + t * 256;
    float s = 0.f;
#pragma unroll 8
    for (int c = 0; c < 256; c += 4) {
        float4 w = *(const float4*)&wr[c];
        s += w.x * vl[c] + w.y * vl[c + 1] + w.z * vl[c + 2] + w.w * vl[c + 3];
    }
    float inv = pg[t] / sqrtf(pvar[t] + EPSF);
    A[b * 256 + t] = s * inv;
    if (b == 0) B0[t] = pb[t] - pm[t] * inv;
}

// ---------------------------------------------------------------------------
// k_cvt: generic fp32 -> bf16 copy (flat, float4 granularity), optional scale
__global__ __launch_bounds__(256) void k_cvt(const float* __restrict__ src,
                                             __bf16* __restrict__ dst, float sc) {
    int e = blockIdx.x * 256 + threadIdx.x;
    float4 vv = *(const float4*)&src[e << 2];
    bf16x4 p;
    p[0] = (__bf16)(vv.x * sc); p[1] = (__bf16)(vv.y * sc);
    p[2] = (__bf16)(vv.z * sc); p[3] = (__bf16)(vv.w * sc);
    *(bf16x4*)&dst[e << 2] = p;
}

// ---------------------------------------------------------------------------
// k_im2col: x fp32 [b][c][n] -> Pb bf16 [b][m][kappa], kappa = c*16+p*4+q,
// m = hm*32+wm (stride-4 patches are a pure permutation).  No LDS needed:
// loads are 8 streams x 128B-contiguous per instr; stores 256B chunks.
// grid = b(2) * hm(32) * ccg(4) = 256 blocks.
__global__ __launch_bounds__(256) void k_im2col(const float* __restrict__ x,
                                                __bf16* __restrict__ Pb) {
    int t = threadIdx.x, bid = blockIdx.x;
    int b = bid >> 7, hm = (bid >> 2) & 31, ccg = bid & 3;
    int wm = t >> 3, c8 = t & 7;
    __bf16* dst_row = Pb + (((size_t)(b << 10) + (hm << 5) + wm) << 12);
#pragma unroll 2
    for (int cci = 0; cci < 8; ++cci) {
        int c = (ccg << 6) + (cci << 3) + c8;
        const float* src = x + ((size_t)(b * 256 + c) << 14) + (hm << 9) + (wm << 2);
        bf16x8 o0, o1;
#pragma unroll
        for (int p = 0; p < 2; ++p) {
            float4 vv = *(const float4*)&src[p << 7];
            o0[p * 4 + 0] = (__bf16)vv.x; o0[p * 4 + 1] = (__bf16)vv.y;
            o0[p * 4 + 2] = (__bf16)vv.z; o0[p * 4 + 3] = (__bf16)vv.w;
        }
#pragma unroll
        for (int p = 0; p < 2; ++p) {
            float4 vv = *(const float4*)&src[(p + 2) << 7];
            o1[p * 4 + 0] = (__bf16)vv.x; o1[p * 4 + 1] = (__bf16)vv.y;
            o1[p * 4 + 2] = (__bf16)vv.z; o1[p * 4 + 3] = (__bf16)vv.w;
        }
        *(bf16x8*)&dst_row[c << 4] = o0;
        *(bf16x8*)&dst_row[(c << 4) + 8] = o1;
    }
}

// ---------------------------------------------------------------------------
// k_conv1: MFMA GEMM  xr_part[m][o] = sum_kappa Pb[m][kappa]*wsrb[o][kappa].
// Split-K=4.  Block: 4 waves, tile 32m x 256o (wave o-split).  Direct global
// fragment loads (both operands in row-major-K layout).
// grid = ks(4) * mt(32) * b(2) = 256.
__global__ __launch_bounds__(256) void k_conv1(const __bf16* __restrict__ Pb,
                                               const __bf16* __restrict__ wsrb,
                                               float* __restrict__ xrp) {
    const int t = threadIdx.x, bid = blockIdx.x;
    const int b = bid & 1, mt = (bid >> 1) & 31, ks = bid >> 6;
    const int w = t >> 6, lane = t & 63, ln = lane & 15, quad = lane >> 4;
    f32x4 acc[2][4];
#pragma unroll
    for (int nt = 0; nt < 2; ++nt)
#pragma unroll
        for (int ot = 0; ot < 4; ++ot) acc[nt][ot] = (f32x4){0.f, 0.f, 0.f, 0.f};
    const __bf16* pa = Pb + (((size_t)(b << 10) + (mt << 5) + ln) << 12) + (ks << 10) + (quad << 3);
    const __bf16* pbm = wsrb + (((size_t)(w << 6) + ln) << 12) + (ks << 10) + (quad << 3);
#pragma unroll 2
    for (int cc = 0; cc < 32; ++cc) {
        const int cb = cc << 5;
        bf16x8 af[2], bfr[4];
#pragma unroll
        for (int nt = 0; nt < 2; ++nt) af[nt] = *(const bf16x8*)&pa[(nt << 16) + cb];
#pragma unroll
        for (int ot = 0; ot < 4; ++ot) bfr[ot] = *(const bf16x8*)&pbm[(ot << 16) + cb];
#pragma unroll
        for (int nt = 0; nt < 2; ++nt)
#pragma unroll
            for (int ot = 0; ot < 4; ++ot)
                acc[nt][ot] = __builtin_amdgcn_mfma_f32_16x16x32_bf16(af[nt], bfr[ot],
                                                                     acc[nt][ot], 0, 0, 0);
    }
    // store partials: xrp[((ks*2+b)*1024 + m)*256 + o]
    float* dst = xrp + (((size_t)((ks << 1) + b) << 10) << 8);
#pragma unroll
    for (int nt = 0; nt < 2; ++nt)
#pragma unroll
        for (int ot = 0; ot < 4; ++ot)
#pragma unroll
            for (int r = 0; r < 4; ++r) {
                int m = (mt << 5) + (nt << 4) + (quad << 2) + r;
                int o = (w << 6) + (ot << 4) + ln;
                dst[m * 256 + o] = acc[nt][ot][r];
            }
}

// ---------------------------------------------------------------------------
// k_comb2: xrb[b][m][c] = bf16(BN(sum_ks xrp)).  grid = 512.
__global__ __launch_bounds__(256) void k_comb2(const float* __restrict__ xrp,
                                               const float* __restrict__ sg,
                                               const float* __restrict__ sb,
                                               const float* __restrict__ smn,
                                               const float* __restrict__ svar,
                                               __bf16* __restrict__ xrb) {
    int t = threadIdx.x, bid = blockIdx.x;
    int b = bid >> 8, m = ((bid & 255) << 2) + (t >> 6);
    int o4 = (t & 63) << 2;
    size_t base = (((size_t)b << 10) + m) << 8;
    float4 s0 = *(const float4*)&xrp[base + o4];
    float4 s1 = *(const float4*)&xrp[524288 + base + o4];
    float4 s2 = *(const float4*)&xrp[1048576 + base + o4];
    float4 s3 = *(const float4*)&xrp[1572864 + base + o4];
    float4 g = *(const float4*)&sg[o4];
    float4 vr = *(const float4*)&svar[o4];
    float4 mn = *(const float4*)&smn[o4];
    float4 bt = *(const float4*)&sb[o4];
    bf16x4 r;
    r[0] = (__bf16)((s0.x + s1.x + s2.x + s3.x - mn.x) * (g.x / sqrtf(vr.x + EPSF)) + bt.x);
    r[1] = (__bf16)((s0.y + s1.y + s2.y + s3.y - mn.y) * (g.y / sqrtf(vr.y + EPSF)) + bt.y);
    r[2] = (__bf16)((s0.z + s1.z + s2.z + s3.z - mn.z) * (g.z / sqrtf(vr.z + EPSF)) + bt.z);
    r[3] = (__bf16)((s0.w + s1.w + s2.w + s3.w - mn.w) * (g.w / sqrtf(vr.w + EPSF)) + bt.w);
    *(bf16x4*)&xrb[base + o4] = r;
}

// ---------------------------------------------------------------------------
// k_kmat2: MFMA GEMM  kkT[b][m][o] = bf16( sum_c xrb[m][c] * wkb[o][c] ).
// SCALE folded into wkb.  Block: 4 waves, tile 64m x 256o.  grid = 32.
__global__ __launch_bounds__(256) void k_kmat2(const __bf16* __restrict__ xrb,
                                               const __bf16* __restrict__ wkb,
                                               __bf16* __restrict__ kkT) {
    const int t = threadIdx.x, bid = blockIdx.x;
    const int b = bid >> 4, mt = bid & 15;
    const int w = t >> 6, lane = t & 63, ln = lane & 15, quad = lane >> 4;
    f32x4 acc[4][4];
#pragma unroll
    for (int nt = 0; nt < 4; ++nt)
#pragma unroll
        for (int ot = 0; ot < 4; ++ot) acc[nt][ot] = (f32x4){0.f, 0.f, 0.f, 0.f};
    const __bf16* pa = xrb + ((((size_t)b << 10) + (mt << 6) + ln) << 8) + (quad << 3);
    const __bf16* pbm = wkb + (((w << 6) + ln) << 8) + (quad << 3);
#pragma unroll 2
    for (int cc = 0; cc < 8; ++cc) {
        const int cb = cc << 5;
        bf16x8 af[4], bfr[4];
#pragma unroll
        for (int nt = 0; nt < 4; ++nt) af[nt] = *(const bf16x8*)&pa[(nt << 12) + cb];
#pragma unroll
        for (int ot = 0; ot < 4; ++ot) bfr[ot] = *(const bf16x8*)&pbm[(ot << 12) + cb];
#pragma unroll
        for (int nt = 0; nt < 4; ++nt)
#pragma unroll
            for (int ot = 0; ot < 4; ++ot)
                acc[nt][ot] = __builtin_amdgcn_mfma_f32_16x16x32_bf16(af[nt], bfr[ot],
                                                                     acc[nt][ot], 0, 0, 0);
    }
    __bf16* dst = kkT + (((size_t)b << 10) << 8);
#pragma unroll
    for (int nt = 0; nt < 4; ++nt)
#pragma unroll
        for (int ot = 0; ot < 4; ++ot)
#pragma unroll
            for (int r = 0; r < 4; ++r) {
                int m = (mt << 6) + (nt << 4) + (quad << 2) + r;
                int o = (w << 6) + (ot << 4) + ln;
                dst[m * 256 + o] = (__bf16)acc[nt][ot][r];
            }
}

// ---------------------------------------------------------------------------
// k_xt: x fp32 [b][c][n] -> xT bf16 [b][n][c]  (LDS-tiled transpose)
__global__ __launch_bounds__(256) void k_xt(const float* __restrict__ x,
                                            __bf16* __restrict__ xT) {
    __shared__ float ts[32 * 132];
    int t = threadIdx.x, bid = blockIdx.x;
    int b = bid >> 7, n0 = (bid & 127) << 7;
    for (int s8 = 0; s8 < 8; ++s8) {
        int c0 = s8 << 5;
        __syncthreads();
#pragma unroll
        for (int i = 0; i < 4; ++i) {
            int e = t + (i << 8);
            int c = e >> 5, n4 = (e & 31) << 2;
            *(float4*)&ts[c * 132 + n4] =
                *(const float4*)&x[((size_t)(b * 256 + c0 + c) << 14) + n0 + n4];
        }
        __syncthreads();
        int n = t >> 1, ch = (t & 1) << 4;
        bf16x8 p0, p1;
#pragma unroll
        for (int j = 0; j < 8; ++j) p0[j] = (__bf16)ts[(ch + j) * 132 + n];
#pragma unroll
        for (int j = 0; j < 8; ++j) p1[j] = (__bf16)ts[(ch + 8 + j) * 132 + n];
        __bf16* dst = xT + ((size_t)(b * 16384 + n0 + n) << 8) + c0 + ch;
        *(bf16x8*)dst = p0;
        *(bf16x8*)(dst + 8) = p1;
    }
}

// ---------------------------------------------------------------------------
// k_scores2: fused MFMA q-GEMM + MFMA scores + max + head-sum + rank-1 epilogue.
// kkT layout: bf16 [b][m][o=h*32+d].  Grid = 512.
__global__ __launch_bounds__(256) void k_scores2(const __bf16* __restrict__ xT,
                                                 const __bf16* __restrict__ wqb,
                                                 const __bf16* __restrict__ kkT,
                                                 const float* __restrict__ A,
                                                 const float* __restrict__ B0,
                                                 float* __restrict__ out) {
    __shared__ __align__(16) __bf16 qs[64 * 264];
    __shared__ float smax[256];
    __shared__ float ss[64];
    __shared__ float sA[256], sB[256];
    const int t = threadIdx.x;
    const int w = t >> 6;
    const int lane = t & 63;
    const int ln = lane & 15;
    const int quad = lane >> 4;
    const int b = blockIdx.x >> 8;
    const int n0 = (blockIdx.x & 255) << 6;
    if (t < 64) ss[t] = 0.f;

    // ---------------- q phase ----------------
    f32x4 acc[4][4];
#pragma unroll
    for (int nt = 0; nt < 4; ++nt)
#pragma unroll
        for (int ot = 0; ot < 4; ++ot) acc[nt][ot] = (f32x4){0.f, 0.f, 0.f, 0.f};

    for (int cc = 0; cc < 8; ++cc) {
        const int cb = (cc << 5) + (quad << 3);
        bf16x8 af[4], bfr[4];
#pragma unroll
        for (int nt = 0; nt < 4; ++nt)
            af[nt] = *(const bf16x8*)&xT[((size_t)(b * 16384 + n0 + (nt << 4) + ln) << 8) + cb];
#pragma unroll
        for (int ot = 0; ot < 4; ++ot)
            bfr[ot] = *(const bf16x8*)&wqb[(((w << 6) + (ot << 4) + ln) << 8) + cb];
#pragma unroll
        for (int nt = 0; nt < 4; ++nt)
#pragma unroll
            for (int ot = 0; ot < 4; ++ot)
                acc[nt][ot] = __builtin_amdgcn_mfma_f32_16x16x32_bf16(af[nt], bfr[ot],
                                                                      acc[nt][ot], 0, 0, 0);
    }
#pragma unroll
    for (int nt = 0; nt < 4; ++nt)
#pragma unroll
        for (int ot = 0; ot < 4; ++ot)
#pragma unroll
            for (int r = 0; r < 4; ++r)
                qs[((nt << 4) + (quad << 2) + r) * 264 + (w << 6) + (ot << 4) + ln] =
                    (__bf16)acc[nt][ot][r];
    __syncthreads();

    // ---------------- score phase ----------------
    const f32x4 zf = {0.f, 0.f, 0.f, 0.f};
    for (int h = 0; h < 8; ++h) {
        bf16x8 qa[4];
#pragma unroll
        for (int nt = 0; nt < 4; ++nt)
            qa[nt] = *(const bf16x8*)&qs[((nt << 4) + ln) * 264 + (h << 5) + (quad << 3)];
        f32x4 mx[4];
#pragma unroll
        for (int nt = 0; nt < 4; ++nt) mx[nt] = (f32x4){-INFINITY, -INFINITY, -INFINITY, -INFINITY};
        const __bf16* kb_base = kkT + (((size_t)b << 10) << 8) + (h << 5) + (quad << 3);
#pragma unroll 2
        for (int i = 0; i < 16; ++i) {
            const int m = ((w << 4) + i) << 4;
            bf16x8 kb = *(const bf16x8*)&kb_base[(m + ln) << 8];
#pragma unroll
            for (int nt = 0; nt < 4; ++nt) {
                f32x4 d = __builtin_amdgcn_mfma_f32_16x16x32_bf16(qa[nt], kb, zf, 0, 0, 0);
                mx[nt][0] = fmaxf(mx[nt][0], d[0]);
                mx[nt][1] = fmaxf(mx[nt][1], d[1]);
                mx[nt][2] = fmaxf(mx[nt][2], d[2]);
                mx[nt][3] = fmaxf(mx[nt][3], d[3]);
            }
        }
#pragma unroll
        for (int nt = 0; nt < 4; ++nt) {
#pragma unroll
            for (int st = 1; st < 16; st <<= 1) {
                mx[nt][0] = fmaxf(mx[nt][0], __shfl_xor(mx[nt][0], st, 64));
                mx[nt][1] = fmaxf(mx[nt][1], __shfl_xor(mx[nt][1], st, 64));
                mx[nt][2] = fmaxf(mx[nt][2], __shfl_xor(mx[nt][2], st, 64));
                mx[nt][3] = fmaxf(mx[nt][3], __shfl_xor(mx[nt][3], st, 64));
            }
        }
        if (ln == 0) {
#pragma unroll
            for (int nt = 0; nt < 4; ++nt)
#pragma unroll
                for (int r = 0; r < 4; ++r)
                    smax[(w << 6) + (nt << 4) + (quad << 2) + r] = mx[nt][r];
        }
        __syncthreads();
        if (t < 64) {
            float vv = fmaxf(fmaxf(smax[t], smax[64 + t]), fmaxf(smax[128 + t], smax[192 + t]));
            ss[t] += vv;
        }
        __syncthreads();
    }

    // ---------------- epilogue ----------------
    sA[t] = A[b * 256 + t];
    sB[t] = B0[t];
    __syncthreads();
#pragma unroll
    for (int i = 0; i < 16; ++i) {
        int e = t + (i << 8);
        int c = e >> 4, n4 = (e & 15) << 2;
        float4 s4 = *(const float4*)&ss[n4];
        float a = sA[c], bb = sB[c];
        float4 o4 = make_float4(fmaf(a, s4.x, bb), fmaf(a, s4.y, bb),
                                fmaf(a, s4.z, bb), fmaf(a, s4.w, bb));
        *(float4*)&out[((size_t)(b * 256 + c) << 14) + n0 + n4] = o4;
    }
}

// ---------------------------------------------------------------------------
extern "C" void kernel_launch(void* const* d_in, const int* in_sizes, int n_in,
                              void* d_out, int out_size, void* d_ws, size_t ws_size,
                              hipStream_t stream) {
    const float* x    = (const float*)d_in[0];
    const float* wq   = (const float*)d_in[1];
    const float* wk   = (const float*)d_in[2];
    const float* wsr  = (const float*)d_in[3];
    const float* sg   = (const float*)d_in[4];
    const float* sb   = (const float*)d_in[5];
    const float* smn  = (const float*)d_in[6];
    const float* svr  = (const float*)d_in[7];
    const float* wproj= (const float*)d_in[8];
    const float* pg   = (const float*)d_in[9];
    const float* pb   = (const float*)d_in[10];
    const float* pm   = (const float*)d_in[11];
    const float* pvr  = (const float*)d_in[12];
    float* out = (float*)d_out;

    // workspace carve (bytes), ~28.5 MB peak.  xT aliases Pb (dead after conv1).
    char* W = (char*)d_ws;
    float*  w_v   = (float*) (W + 0);          // 512 f
    float*  w_A   = (float*) (W + 4096);       // 512 f
    float*  w_B0  = (float*) (W + 8192);       // 256 f
    __bf16* w_wqb = (__bf16*)(W + 16384);      // 128 KB
    __bf16* w_wkb = (__bf16*)(W + 147456);     // 128 KB
    __bf16* w_wsrb= (__bf16*)(W + 278528);     // 2 MB
    __bf16* w_xrb = (__bf16*)(W + 2375680);    // 512 KB  (bf16 2x1024x256)
    __bf16* w_kkT = (__bf16*)(W + 2899968);    // 1 MB    (bf16 2x1024x256)
    float*  w_xrp = (float*) (W + 3948544);    // 8 MB    (fp32 4x2x1024x256)
    __bf16* w_Pb  = (__bf16*)(W + 12337152);   // 16 MB   (bf16 2x1024x4096)
    __bf16* w_xT  = (__bf16*)(W + 12337152);   // 16 MB   — alias over Pb

    k_mean<<<512, 256, 0, stream>>>(x, w_v);
    k_ab<<<2, 256, 0, stream>>>(w_v, wproj, pg, pb, pm, pvr, w_A, w_B0);
    k_cvt<<<64, 256, 0, stream>>>(wq, w_wqb, 1.0f);
    k_cvt<<<64, 256, 0, stream>>>(wk, w_wkb, SCALE);
    k_cvt<<<1024, 256, 0, stream>>>(wsr, w_wsrb, 1.0f);
    k_im2col<<<256, 256, 0, stream>>>(x, w_Pb);
    k_conv1<<<256, 256, 0, stream>>>(w_Pb, w_wsrb, w_xrp);
    k_comb2<<<512, 256, 0, stream>>>(w_xrp, sg, sb, smn, svr, w_xrb);
    k_kmat2<<<32, 256, 0, stream>>>(w_xrb, w_wkb, w_kkT);
    k_xt<<<256, 256, 0, stream>>>(x, w_xT);    // clobbers Pb (dead)
    k_scores2<<<512, 256, 0, stream>>>(w_xT, w_wqb, w_kkT, w_A, w_B0, out);
}

// Round 5
// 208.829 us; speedup vs baseline: 3.4714x; 1.1832x over previous
//
#include <hip/hip_runtime.h>
#include <hip/hip_bf16.h>
#include <math.h>

// Problem constants (B=2, C=256, H=W=128, N=16384, SR=4, HEADS=8, hd=32, M=1024)
#define EPSF 1e-5f
#define SCALE 0.17677669529663687f  // 1/sqrt(32)

typedef __bf16 bf16x8 __attribute__((ext_vector_type(8)));
typedef __bf16 bf16x4 __attribute__((ext_vector_type(4)));
typedef float f32x4 __attribute__((ext_vector_type(4)));

// Fragment-major layouts (MFMA 16x16x32, A/B frag = [row/col ln<16][k=quad*8+j]):
//   xTf : x^T  [b][n_tile(1024)][cc(8)][lane(64)][j(8)]   elem idx = ((nt*8+cc)*64+lane)*8+j
//   wqf : w_q  [o_tile(16)][cc(8)][lane][j]
//   Pbf : P    [b][m_tile(64)][cc(128)][lane][j]
//   wsrf: w_sr [o_tile(16)][cc(128)][lane][j]
//   kkbh: k    [b][h(8)][m(1024)][d(32)]                  (A-frag rows contiguous)

// ---------------------------------------------------------------------------
// k_ab: A[b,o] = (W_proj v)[b,o] * inv[o];  B0[o] = beta[o] - mean[o]*inv[o]
// v holds SUMS over n (accumulated by k_im2col atomics) -> divide by 16384.
__global__ __launch_bounds__(256) void k_ab(const float* __restrict__ v,
                                            const float* __restrict__ wproj,
                                            const float* __restrict__ pg,
                                            const float* __restrict__ pb,
                                            const float* __restrict__ pm,
                                            const float* __restrict__ pvar,
                                            float* __restrict__ A,
                                            float* __restrict__ B0) {
    __shared__ float vl[256];
    int t = threadIdx.x, b = blockIdx.x;
    vl[t] = v[b * 256 + t] * (1.0f / 16384.0f);
    __syncthreads();
    const float* wr = wproj + t * 256;
    float s = 0.f;
#pragma unroll 8
    for (int c = 0; c < 256; c += 4) {
        float4 w = *(const float4*)&wr[c];
        s += w.x * vl[c] + w.y * vl[c + 1] + w.z * vl[c + 2] + w.w * vl[c + 3];
    }
    float inv = pg[t] / sqrtf(pvar[t] + EPSF);
    A[b * 256 + t] = s * inv;
    if (b == 0) B0[t] = pb[t] - pm[t] * inv;
}

// ---------------------------------------------------------------------------
// k_wprep: weight conversions + v zeroing, one launch, 576 blocks.
// blocks 0..31: wq -> wqf (frag-major) [+ block 0 zeroes v];
// 32..63: wk -> wkb flat *SCALE; 64..575: wsr -> wsrf (frag-major).
__global__ __launch_bounds__(256) void k_wprep(const float* __restrict__ wq,
                                               const float* __restrict__ wk,
                                               const float* __restrict__ wsr,
                                               __bf16* __restrict__ wqf,
                                               __bf16* __restrict__ wkb,
                                               __bf16* __restrict__ wsrf,
                                               float* __restrict__ v) {
    int bi = blockIdx.x, t = threadIdx.x;
    if (bi < 32) {
        if (bi == 0) { v[t] = 0.f; v[256 + t] = 0.f; }
        int tt = bi * 256 + t;              // 0..8191
        int o = tt >> 5, chunk = tt & 31;   // c = chunk*8 + j
        float4 v0 = *(const float4*)&wq[o * 256 + (chunk << 3)];
        float4 v1 = *(const float4*)&wq[o * 256 + (chunk << 3) + 4];
        bf16x8 p;
        p[0] = (__bf16)v0.x; p[1] = (__bf16)v0.y; p[2] = (__bf16)v0.z; p[3] = (__bf16)v0.w;
        p[4] = (__bf16)v1.x; p[5] = (__bf16)v1.y; p[6] = (__bf16)v1.z; p[7] = (__bf16)v1.w;
        int cc = chunk >> 2, quad = chunk & 3;
        *(bf16x8*)&wqf[(((((o >> 4) << 3) + cc) << 6) + (quad << 4) + (o & 15)) << 3] = p;
    } else if (bi < 64) {
        int e = (bi - 32) * 256 + t;        // 8 elems each
        float4 v0 = *(const float4*)&wk[e << 3];
        float4 v1 = *(const float4*)&wk[(e << 3) + 4];
        bf16x8 p;
        p[0] = (__bf16)(v0.x * SCALE); p[1] = (__bf16)(v0.y * SCALE);
        p[2] = (__bf16)(v0.z * SCALE); p[3] = (__bf16)(v0.w * SCALE);
        p[4] = (__bf16)(v1.x * SCALE); p[5] = (__bf16)(v1.y * SCALE);
        p[6] = (__bf16)(v1.z * SCALE); p[7] = (__bf16)(v1.w * SCALE);
        *(bf16x8*)&wkb[e << 3] = p;
    } else {
        int tt = (bi - 64) * 256 + t;       // 0..131071
        int o = tt >> 9, chunk = tt & 511;  // kappa = chunk*8 + j  (4096 per o)
        float4 v0 = *(const float4*)&wsr[o * 4096 + (chunk << 3)];
        float4 v1 = *(const float4*)&wsr[o * 4096 + (chunk << 3) + 4];
        bf16x8 p;
        p[0] = (__bf16)v0.x; p[1] = (__bf16)v0.y; p[2] = (__bf16)v0.z; p[3] = (__bf16)v0.w;
        p[4] = (__bf16)v1.x; p[5] = (__bf16)v1.y; p[6] = (__bf16)v1.z; p[7] = (__bf16)v1.w;
        int cc = chunk >> 2, quad = chunk & 3;
        *(bf16x8*)&wsrf[(((((o >> 4) << 7) + cc) << 6) + (quad << 4) + (o & 15)) << 3] = p;
    }
}

// ---------------------------------------------------------------------------
// k_im2col: x fp32 [b][c][n] -> Pbf (fragment-major) + v-sum atomics (fused mean).
// grid = b(2) * hm(32) * ccg(4) = 256.  v zeroed by k_wprep.
__global__ __launch_bounds__(256) void k_im2col(const float* __restrict__ x,
                                                __bf16* __restrict__ Pbf,
                                                float* __restrict__ v) {
    __shared__ float csum[64];
    int t = threadIdx.x, bid = blockIdx.x;
    int b = bid >> 7, hm = (bid >> 2) & 31, ccg = bid & 3;
    int wm = t >> 3, c8 = t & 7;
    if (t < 64) csum[t] = 0.f;
    __syncthreads();
    const int mtile = (hm << 1) + (wm >> 4);
    const int ln = wm & 15;
#pragma unroll 2
    for (int cci = 0; cci < 8; ++cci) {
        int c = (ccg << 6) + (cci << 3) + c8;
        const float* src = x + ((size_t)(b * 256 + c) << 14) + (hm << 9) + (wm << 2);
        bf16x8 o0, o1;
        float s = 0.f;
#pragma unroll
        for (int p = 0; p < 2; ++p) {
            float4 vv = *(const float4*)&src[p << 7];
            s += vv.x + vv.y + vv.z + vv.w;
            o0[p * 4 + 0] = (__bf16)vv.x; o0[p * 4 + 1] = (__bf16)vv.y;
            o0[p * 4 + 2] = (__bf16)vv.z; o0[p * 4 + 3] = (__bf16)vv.w;
        }
#pragma unroll
        for (int p = 0; p < 2; ++p) {
            float4 vv = *(const float4*)&src[(p + 2) << 7];
            s += vv.x + vv.y + vv.z + vv.w;
            o1[p * 4 + 0] = (__bf16)vv.x; o1[p * 4 + 1] = (__bf16)vv.y;
            o1[p * 4 + 2] = (__bf16)vv.z; o1[p * 4 + 3] = (__bf16)vv.w;
        }
        // kappa = c*16 + j (o0) / c*16+8+j (o1): cc=c>>1, quad=(c&1)*2 (+1 for o1)
        size_t d0 = (((((size_t)(b * 64 + mtile) << 7) + (c >> 1)) << 6) +
                     (((c & 1) << 1) << 4) + ln) << 3;
        *(bf16x8*)&Pbf[d0] = o0;
        *(bf16x8*)&Pbf[d0 + 128] = o1;
        atomicAdd(&csum[(cci << 3) + c8], s);
    }
    __syncthreads();
    if (t < 64) atomicAdd(&v[b * 256 + (ccg << 6) + t], csum[t]);
}

// ---------------------------------------------------------------------------
// k_conv1: MFMA GEMM  xrp[m][o] = Pbf x wsrf, split-K=4.  All fragment loads
// wave-coalesced 1KB.  grid = ks(4) * mt(32) * b(2) = 256.
__global__ __launch_bounds__(256) void k_conv1(const __bf16* __restrict__ Pbf,
                                               const __bf16* __restrict__ wsrf,
                                               float* __restrict__ xrp) {
    const int t = threadIdx.x, bid = blockIdx.x;
    const int b = bid & 1, mt = (bid >> 1) & 31, ks = bid >> 6;
    const int w = t >> 6, lane = t & 63, ln = lane & 15, quad = lane >> 4;
    f32x4 acc[2][4];
#pragma unroll
    for (int nt = 0; nt < 2; ++nt)
#pragma unroll
        for (int ot = 0; ot < 4; ++ot) acc[nt][ot] = (f32x4){0.f, 0.f, 0.f, 0.f};
    const __bf16* pa = Pbf + (((((size_t)(b * 64 + mt * 2)) << 7) + (ks << 5)) << 9) + (lane << 3);
    const __bf16* pbm = wsrf + ((((size_t)(w << 2) << 7) + (ks << 5)) << 9) + (lane << 3);
#pragma unroll 4
    for (int cci = 0; cci < 32; ++cci) {
        const int cb = cci << 9;
        bf16x8 af[2], bfr[4];
#pragma unroll
        for (int nt = 0; nt < 2; ++nt) af[nt] = *(const bf16x8*)&pa[(nt << 16) + cb];
#pragma unroll
        for (int ot = 0; ot < 4; ++ot) bfr[ot] = *(const bf16x8*)&pbm[(ot << 16) + cb];
#pragma unroll
        for (int nt = 0; nt < 2; ++nt)
#pragma unroll
            for (int ot = 0; ot < 4; ++ot)
                acc[nt][ot] = __builtin_amdgcn_mfma_f32_16x16x32_bf16(af[nt], bfr[ot],
                                                                     acc[nt][ot], 0, 0, 0);
    }
    float* dst = xrp + (((size_t)((ks << 1) + b) << 10) << 8);
#pragma unroll
    for (int nt = 0; nt < 2; ++nt)
#pragma unroll
        for (int ot = 0; ot < 4; ++ot)
#pragma unroll
            for (int r = 0; r < 4; ++r) {
                int m = (mt << 5) + (nt << 4) + (quad << 2) + r;
                int o = (w << 6) + (ot << 4) + ln;
                dst[m * 256 + o] = acc[nt][ot][r];
            }
}

// ---------------------------------------------------------------------------
// k_comb2: xrb[b][m][c] = bf16(BN(sum_ks xrp)).  grid = 512.
__global__ __launch_bounds__(256) void k_comb2(const float* __restrict__ xrp,
                                               const float* __restrict__ sg,
                                               const float* __restrict__ sb,
                                               const float* __restrict__ smn,
                                               const float* __restrict__ svar,
                                               __bf16* __restrict__ xrb) {
    int t = threadIdx.x, bid = blockIdx.x;
    int b = bid >> 8, m = ((bid & 255) << 2) + (t >> 6);
    int o4 = (t & 63) << 2;
    size_t base = (((size_t)b << 10) + m) << 8;
    float4 s0 = *(const float4*)&xrp[base + o4];
    float4 s1 = *(const float4*)&xrp[524288 + base + o4];
    float4 s2 = *(const float4*)&xrp[1048576 + base + o4];
    float4 s3 = *(const float4*)&xrp[1572864 + base + o4];
    float4 g = *(const float4*)&sg[o4];
    float4 vr = *(const float4*)&svar[o4];
    float4 mn = *(const float4*)&smn[o4];
    float4 bt = *(const float4*)&sb[o4];
    bf16x4 r;
    r[0] = (__bf16)((s0.x + s1.x + s2.x + s3.x - mn.x) * (g.x / sqrtf(vr.x + EPSF)) + bt.x);
    r[1] = (__bf16)((s0.y + s1.y + s2.y + s3.y - mn.y) * (g.y / sqrtf(vr.y + EPSF)) + bt.y);
    r[2] = (__bf16)((s0.z + s1.z + s2.z + s3.z - mn.z) * (g.z / sqrtf(vr.z + EPSF)) + bt.z);
    r[3] = (__bf16)((s0.w + s1.w + s2.w + s3.w - mn.w) * (g.w / sqrtf(vr.w + EPSF)) + bt.w);
    *(bf16x4*)&xrb[base + o4] = r;
}

// ---------------------------------------------------------------------------
// k_kmat2: MFMA GEMM  kkbh[b][h][m][d] = bf16( xrb x wkb ).  grid = 32.
__global__ __launch_bounds__(256) void k_kmat2(const __bf16* __restrict__ xrb,
                                               const __bf16* __restrict__ wkb,
                                               __bf16* __restrict__ kkbh) {
    const int t = threadIdx.x, bid = blockIdx.x;
    const int b = bid >> 4, mt = bid & 15;
    const int w = t >> 6, lane = t & 63, ln = lane & 15, quad = lane >> 4;
    f32x4 acc[4][4];
#pragma unroll
    for (int nt = 0; nt < 4; ++nt)
#pragma unroll
        for (int ot = 0; ot < 4; ++ot) acc[nt][ot] = (f32x4){0.f, 0.f, 0.f, 0.f};
    const __bf16* pa = xrb + ((((size_t)b << 10) + (mt << 6) + ln) << 8) + (quad << 3);
    const __bf16* pbm = wkb + (((w << 6) + ln) << 8) + (quad << 3);
#pragma unroll 2
    for (int cc = 0; cc < 8; ++cc) {
        const int cb = cc << 5;
        bf16x8 af[4], bfr[4];
#pragma unroll
        for (int nt = 0; nt < 4; ++nt) af[nt] = *(const bf16x8*)&pa[(nt << 12) + cb];
#pragma unroll
        for (int ot = 0; ot < 4; ++ot) bfr[ot] = *(const bf16x8*)&pbm[(ot << 12) + cb];
#pragma unroll
        for (int nt = 0; nt < 4; ++nt)
#pragma unroll
            for (int ot = 0; ot < 4; ++ot)
                acc[nt][ot] = __builtin_amdgcn_mfma_f32_16x16x32_bf16(af[nt], bfr[ot],
                                                                     acc[nt][ot], 0, 0, 0);
    }
#pragma unroll
    for (int nt = 0; nt < 4; ++nt)
#pragma unroll
        for (int ot = 0; ot < 4; ++ot)
#pragma unroll
            for (int r = 0; r < 4; ++r) {
                int m = (mt << 6) + (nt << 4) + (quad << 2) + r;
                int h = (w << 1) + (ot >> 1);
                int d = ((ot & 1) << 4) + ln;
                kkbh[(((size_t)(b * 8 + h)) << 15) + (m << 5) + d] = (__bf16)acc[nt][ot][r];
            }
}

// ---------------------------------------------------------------------------
// k_xt: x fp32 [b][c][n] -> xTf fragment-major.  grid = 256.
__global__ __launch_bounds__(256) void k_xt(const float* __restrict__ x,
                                            __bf16* __restrict__ xTf) {
    __shared__ float ts[32 * 132];
    int t = threadIdx.x, bid = blockIdx.x;
    int b = bid >> 7, n0 = (bid & 127) << 7;
    const int n = n0 + (t >> 1);
    const int ntile = n >> 4, ln = n & 15;
    const int ch = (t & 1) << 4;  // c-offset within 32-chunk (0 or 16)
    for (int s8 = 0; s8 < 8; ++s8) {
        int c0 = s8 << 5;
        __syncthreads();
#pragma unroll
        for (int i = 0; i < 4; ++i) {
            int e = t + (i << 8);
            int c = e >> 5, n4 = (e & 31) << 2;
            *(float4*)&ts[c * 132 + n4] =
                *(const float4*)&x[((size_t)(b * 256 + c0 + c) << 14) + n0 + n4];
        }
        __syncthreads();
        int nl = t >> 1;
        bf16x8 p0, p1;
#pragma unroll
        for (int j = 0; j < 8; ++j) p0[j] = (__bf16)ts[(ch + j) * 132 + nl];
#pragma unroll
        for (int j = 0; j < 8; ++j) p1[j] = (__bf16)ts[(ch + 8 + j) * 132 + nl];
        int q0 = ch >> 3;  // quad of p0; p1 is q0+1
        size_t base = ((((size_t)(b * 1024 + ntile) << 3) + s8) << 6);
        *(bf16x8*)&xTf[(base + (q0 << 4) + ln) << 3] = p0;
        *(bf16x8*)&xTf[(base + ((q0 + 1) << 4) + ln) << 3] = p1;
    }
}

// ---------------------------------------------------------------------------
// k_scores2: fused MFMA q-GEMM + MFMA scores (k as A -> m in regs) + max +
// head-sum + rank-1 epilogue.  All global frag loads wave-coalesced.
// grid = 512 (b x 256 n-chunks of 64), 4 waves (m-split in score phase).
__global__ __launch_bounds__(256) void k_scores2(const __bf16* __restrict__ xTf,
                                                 const __bf16* __restrict__ wqf,
                                                 const __bf16* __restrict__ kkbh,
                                                 const float* __restrict__ A,
                                                 const float* __restrict__ B0,
                                                 float* __restrict__ out) {
    __shared__ __align__(16) __bf16 qs[64 * 264];
    __shared__ float smax[256];
    __shared__ float ss[64];
    __shared__ float sA[256], sB[256];
    const int t = threadIdx.x;
    const int w = t >> 6;
    const int lane = t & 63;
    const int ln = lane & 15;
    const int quad = lane >> 4;
    const int b = blockIdx.x >> 8;
    const int n0 = (blockIdx.x & 255) << 6;
    if (t < 64) ss[t] = 0.f;

    // ---------------- q phase: q[64n][256o], wave w owns o in [w*64, w*64+64)
    f32x4 acc[4][4];
#pragma unroll
    for (int nt = 0; nt < 4; ++nt)
#pragma unroll
        for (int ot = 0; ot < 4; ++ot) acc[nt][ot] = (f32x4){0.f, 0.f, 0.f, 0.f};
    const __bf16* pa = xTf + (((size_t)(b * 1024 + (n0 >> 4))) << 12) + (lane << 3);
    const __bf16* pbm = wqf + ((size_t)w << 14) + (lane << 3);
#pragma unroll 2
    for (int cc = 0; cc < 8; ++cc) {
        const int cb = cc << 9;
        bf16x8 af[4], bfr[4];
#pragma unroll
        for (int nt = 0; nt < 4; ++nt) af[nt] = *(const bf16x8*)&pa[(nt << 12) + cb];
#pragma unroll
        for (int ot = 0; ot < 4; ++ot) bfr[ot] = *(const bf16x8*)&pbm[(ot << 12) + cb];
#pragma unroll
        for (int nt = 0; nt < 4; ++nt)
#pragma unroll
            for (int ot = 0; ot < 4; ++ot)
                acc[nt][ot] = __builtin_amdgcn_mfma_f32_16x16x32_bf16(af[nt], bfr[ot],
                                                                      acc[nt][ot], 0, 0, 0);
    }
#pragma unroll
    for (int nt = 0; nt < 4; ++nt)
#pragma unroll
        for (int ot = 0; ot < 4; ++ot)
#pragma unroll
            for (int r = 0; r < 4; ++r)
                qs[((nt << 4) + (quad << 2) + r) * 264 + (w << 6) + (ot << 4) + ln] =
                    (__bf16)acc[nt][ot][r];
    __syncthreads();

    // ---------------- score phase: k as A (m rows in regs), q as B (n cols)
    const f32x4 zf = {0.f, 0.f, 0.f, 0.f};
    for (int h = 0; h < 8; ++h) {
        bf16x8 qb[4];
#pragma unroll
        for (int nt = 0; nt < 4; ++nt)
            qb[nt] = *(const bf16x8*)&qs[((nt << 4) + ln) * 264 + (h << 5) + (quad << 3)];
        float rmx[4] = {-INFINITY, -INFINITY, -INFINITY, -INFINITY};
        const __bf16* kb_base = kkbh + ((size_t)(b * 8 + h) << 15) + (ln << 5) + (quad << 3);
#pragma unroll 4
        for (int i = 0; i < 16; ++i) {
            bf16x8 kb = *(const bf16x8*)&kb_base[((w << 8) + (i << 4)) << 5];
#pragma unroll
            for (int nt = 0; nt < 4; ++nt) {
                f32x4 d = __builtin_amdgcn_mfma_f32_16x16x32_bf16(kb, qb[nt], zf, 0, 0, 0);
                rmx[nt] = fmaxf(rmx[nt], fmaxf(fmaxf(d[0], d[1]), fmaxf(d[2], d[3])));
            }
        }
        // reduce across quads (m sub-rows): 2 shuffle stages
#pragma unroll
        for (int nt = 0; nt < 4; ++nt) {
            rmx[nt] = fmaxf(rmx[nt], __shfl_xor(rmx[nt], 16, 64));
            rmx[nt] = fmaxf(rmx[nt], __shfl_xor(rmx[nt], 32, 64));
        }
        if (lane < 16) {
#pragma unroll
            for (int nt = 0; nt < 4; ++nt) smax[(w << 6) + (nt << 4) + lane] = rmx[nt];
        }
        __syncthreads();
        if (t < 64) {
            float vv = fmaxf(fmaxf(smax[t], smax[64 + t]), fmaxf(smax[128 + t], smax[192 + t]));
            ss[t] += vv;
        }
        __syncthreads();
    }

    // ---------------- epilogue: out[b][c][n0..n0+63] = A*s + B0
    sA[t] = A[b * 256 + t];
    sB[t] = B0[t];
    __syncthreads();
#pragma unroll
    for (int i = 0; i < 16; ++i) {
        int e = t + (i << 8);
        int c = e >> 4, n4 = (e & 15) << 2;
        float4 s4 = *(const float4*)&ss[n4];
        float a = sA[c], bb = sB[c];
        float4 o4 = make_float4(fmaf(a, s4.x, bb), fmaf(a, s4.y, bb),
                                fmaf(a, s4.z, bb), fmaf(a, s4.w, bb));
        *(float4*)&out[((size_t)(b * 256 + c) << 14) + n0 + n4] = o4;
    }
}

// ---------------------------------------------------------------------------
extern "C" void kernel_launch(void* const* d_in, const int* in_sizes, int n_in,
                              void* d_out, int out_size, void* d_ws, size_t ws_size,
                              hipStream_t stream) {
    const float* x    = (const float*)d_in[0];
    const float* wq   = (const float*)d_in[1];
    const float* wk   = (const float*)d_in[2];
    const float* wsr  = (const float*)d_in[3];
    const float* sg   = (const float*)d_in[4];
    const float* sb   = (const float*)d_in[5];
    const float* smn  = (const float*)d_in[6];
    const float* svr  = (const float*)d_in[7];
    const float* wproj= (const float*)d_in[8];
    const float* pg   = (const float*)d_in[9];
    const float* pb   = (const float*)d_in[10];
    const float* pm   = (const float*)d_in[11];
    const float* pvr  = (const float*)d_in[12];
    float* out = (float*)d_out;

    char* W = (char*)d_ws;
    float*  w_v   = (float*) (W + 0);          // 512 f (sum accumulators)
    float*  w_A   = (float*) (W + 4096);       // 512 f
    float*  w_B0  = (float*) (W + 8192);       // 256 f
    __bf16* w_wqf = (__bf16*)(W + 16384);      // 128 KB  (frag-major)
    __bf16* w_wkb = (__bf16*)(W + 147456);     // 128 KB  (flat, *SCALE)
    __bf16* w_wsrf= (__bf16*)(W + 278528);     // 2 MB    (frag-major)
    __bf16* w_xrb = (__bf16*)(W + 2375680);    // 512 KB  ([b][m][c])
    __bf16* w_kkbh= (__bf16*)(W + 2899968);    // 1 MB    ([b][h][m][d])
    float*  w_xrp = (float*) (W + 3948544);    // 8 MB    (split-K partials)
    __bf16* w_Pbf = (__bf16*)(W + 12337152);   // 16 MB   (frag-major)
    __bf16* w_xTf = (__bf16*)(W + 12337152);   // 16 MB   — alias (Pbf dead by k_xt)

    k_wprep<<<576, 256, 0, stream>>>(wq, wk, wsr, w_wqf, w_wkb, w_wsrf, w_v);
    k_im2col<<<256, 256, 0, stream>>>(x, w_Pbf, w_v);
    k_ab<<<2, 256, 0, stream>>>(w_v, wproj, pg, pb, pm, pvr, w_A, w_B0);
    k_conv1<<<256, 256, 0, stream>>>(w_Pbf, w_wsrf, w_xrp);
    k_comb2<<<512, 256, 0, stream>>>(w_xrp, sg, sb, smn, svr, w_xrb);
    k_kmat2<<<32, 256, 0, stream>>>(w_xrb, w_wkb, w_kkbh);
    k_xt<<<256, 256, 0, stream>>>(x, w_xTf);   // clobbers Pbf (dead)
    k_scores2<<<512, 256, 0, stream>>>(w_xTf, w_wqf, w_kkbh, w_A, w_B0, out);
}

// Round 6
// 194.770 us; speedup vs baseline: 3.7220x; 1.0722x over previous
//
#include <hip/hip_runtime.h>
#include <hip/hip_bf16.h>
#include <math.h>

// Problem constants (B=2, C=256, H=W=128, N=16384, SR=4, HEADS=8, hd=32, M=1024)
#define EPSF 1e-5f
#define SCALE 0.17677669529663687f  // 1/sqrt(32)

typedef __bf16 bf16x8 __attribute__((ext_vector_type(8)));
typedef __bf16 bf16x4 __attribute__((ext_vector_type(4)));
typedef float f32x4 __attribute__((ext_vector_type(4)));

// Fragment-major layouts (MFMA 16x16x32, A/B frag = [row/col ln<16][k=quad*8+j]):
//   xTf : x^T  [b][n_tile(1024)][cc(8)][lane(64)][j(8)]
//   wqf : w_q  [o_tile(16)][cc(8)][lane][j]
//   Pbf : P    [b][m_tile(64)][cc(128)][lane][j]
//   wsrf: w_sr [o_tile(16)][cc(128)][lane][j]
//   kkbh: k    [b][h(8)][m(1024)][d(32)]

// ---------------------------------------------------------------------------
__global__ __launch_bounds__(256) void k_ab(const float* __restrict__ v,
                                            const float* __restrict__ wproj,
                                            const float* __restrict__ pg,
                                            const float* __restrict__ pb,
                                            const float* __restrict__ pm,
                                            const float* __restrict__ pvar,
                                            float* __restrict__ A,
                                            float* __restrict__ B0) {
    __shared__ float vl[256];
    int t = threadIdx.x, b = blockIdx.x;
    vl[t] = v[b * 256 + t] * (1.0f / 16384.0f);
    __syncthreads();
    const float* wr = wproj + t * 256;
    float s = 0.f;
#pragma unroll 8
    for (int c = 0; c < 256; c += 4) {
        float4 w = *(const float4*)&wr[c];
        s += w.x * vl[c] + w.y * vl[c + 1] + w.z * vl[c + 2] + w.w * vl[c + 3];
    }
    float inv = pg[t] / sqrtf(pvar[t] + EPSF);
    A[b * 256 + t] = s * inv;
    if (b == 0) B0[t] = pb[t] - pm[t] * inv;
}

// ---------------------------------------------------------------------------
// k_wprep: weight conversions + v zeroing.  576 blocks.
__global__ __launch_bounds__(256) void k_wprep(const float* __restrict__ wq,
                                               const float* __restrict__ wk,
                                               const float* __restrict__ wsr,
                                               __bf16* __restrict__ wqf,
                                               __bf16* __restrict__ wkb,
                                               __bf16* __restrict__ wsrf,
                                               float* __restrict__ v) {
    int bi = blockIdx.x, t = threadIdx.x;
    if (bi < 32) {
        if (bi == 0) { v[t] = 0.f; v[256 + t] = 0.f; }
        int tt = bi * 256 + t;
        int o = tt >> 5, chunk = tt & 31;
        float4 v0 = *(const float4*)&wq[o * 256 + (chunk << 3)];
        float4 v1 = *(const float4*)&wq[o * 256 + (chunk << 3) + 4];
        bf16x8 p;
        p[0] = (__bf16)v0.x; p[1] = (__bf16)v0.y; p[2] = (__bf16)v0.z; p[3] = (__bf16)v0.w;
        p[4] = (__bf16)v1.x; p[5] = (__bf16)v1.y; p[6] = (__bf16)v1.z; p[7] = (__bf16)v1.w;
        int cc = chunk >> 2, quad = chunk & 3;
        *(bf16x8*)&wqf[(((((o >> 4) << 3) + cc) << 6) + (quad << 4) + (o & 15)) << 3] = p;
    } else if (bi < 64) {
        int e = (bi - 32) * 256 + t;
        float4 v0 = *(const float4*)&wk[e << 3];
        float4 v1 = *(const float4*)&wk[(e << 3) + 4];
        bf16x8 p;
        p[0] = (__bf16)(v0.x * SCALE); p[1] = (__bf16)(v0.y * SCALE);
        p[2] = (__bf16)(v0.z * SCALE); p[3] = (__bf16)(v0.w * SCALE);
        p[4] = (__bf16)(v1.x * SCALE); p[5] = (__bf16)(v1.y * SCALE);
        p[6] = (__bf16)(v1.z * SCALE); p[7] = (__bf16)(v1.w * SCALE);
        *(bf16x8*)&wkb[e << 3] = p;
    } else {
        int tt = (bi - 64) * 256 + t;
        int o = tt >> 9, chunk = tt & 511;
        float4 v0 = *(const float4*)&wsr[o * 4096 + (chunk << 3)];
        float4 v1 = *(const float4*)&wsr[o * 4096 + (chunk << 3) + 4];
        bf16x8 p;
        p[0] = (__bf16)v0.x; p[1] = (__bf16)v0.y; p[2] = (__bf16)v0.z; p[3] = (__bf16)v0.w;
        p[4] = (__bf16)v1.x; p[5] = (__bf16)v1.y; p[6] = (__bf16)v1.z; p[7] = (__bf16)v1.w;
        int cc = chunk >> 2, quad = chunk & 3;
        *(bf16x8*)&wsrf[(((((o >> 4) << 7) + cc) << 6) + (quad << 4) + (o & 15)) << 3] = p;
    }
}

// ---------------------------------------------------------------------------
// k_im2col: x -> Pbf (frag-major) + v-sum atomics.  grid = 2*32*8 = 512.
__global__ __launch_bounds__(256) void k_im2col(const float* __restrict__ x,
                                                __bf16* __restrict__ Pbf,
                                                float* __restrict__ v) {
    __shared__ float csum[32];
    int t = threadIdx.x, bid = blockIdx.x;
    int b = bid >> 8, hm = (bid >> 3) & 31, ccg = bid & 7;
    int wm = t >> 3, c8 = t & 7;
    if (t < 32) csum[t] = 0.f;
    __syncthreads();
    const int mtile = (hm << 1) + (wm >> 4);
    const int ln = wm & 15;
#pragma unroll
    for (int cci = 0; cci < 4; ++cci) {
        int c = (ccg << 5) + (cci << 3) + c8;
        const float* src = x + ((size_t)(b * 256 + c) << 14) + (hm << 9) + (wm << 2);
        bf16x8 o0, o1;
        float s = 0.f;
#pragma unroll
        for (int p = 0; p < 2; ++p) {
            float4 vv = *(const float4*)&src[p << 7];
            s += vv.x + vv.y + vv.z + vv.w;
            o0[p * 4 + 0] = (__bf16)vv.x; o0[p * 4 + 1] = (__bf16)vv.y;
            o0[p * 4 + 2] = (__bf16)vv.z; o0[p * 4 + 3] = (__bf16)vv.w;
        }
#pragma unroll
        for (int p = 0; p < 2; ++p) {
            float4 vv = *(const float4*)&src[(p + 2) << 7];
            s += vv.x + vv.y + vv.z + vv.w;
            o1[p * 4 + 0] = (__bf16)vv.x; o1[p * 4 + 1] = (__bf16)vv.y;
            o1[p * 4 + 2] = (__bf16)vv.z; o1[p * 4 + 3] = (__bf16)vv.w;
        }
        size_t d0 = (((((size_t)(b * 64 + mtile) << 7) + (c >> 1)) << 6) +
                     (((c & 1) << 1) << 4) + ln) << 3;
        *(bf16x8*)&Pbf[d0] = o0;
        *(bf16x8*)&Pbf[d0 + 128] = o1;
        atomicAdd(&csum[(cci << 3) + c8], s);
    }
    __syncthreads();
    if (t < 32) atomicAdd(&v[b * 256 + (ccg << 5) + t], csum[t]);
}

// ---------------------------------------------------------------------------
// k_conv1: MFMA GEMM, split-K=4, m=16/block.  grid = ks(4)*mt(64)*b(2) = 512.
__global__ __launch_bounds__(256) void k_conv1(const __bf16* __restrict__ Pbf,
                                               const __bf16* __restrict__ wsrf,
                                               float* __restrict__ xrp) {
    const int t = threadIdx.x, bid = blockIdx.x;
    const int b = bid & 1, mt = (bid >> 1) & 63, ks = bid >> 7;
    const int w = t >> 6, lane = t & 63, ln = lane & 15, quad = lane >> 4;
    f32x4 acc[4];
#pragma unroll
    for (int ot = 0; ot < 4; ++ot) acc[ot] = (f32x4){0.f, 0.f, 0.f, 0.f};
    const __bf16* pa = Pbf + ((((size_t)(b * 64 + mt) << 7) + (ks << 5)) << 9) + (lane << 3);
    const __bf16* pbm = wsrf + ((((size_t)(w << 2) << 7) + (ks << 5)) << 9) + (lane << 3);
#pragma unroll 4
    for (int cci = 0; cci < 32; ++cci) {
        const int cb = cci << 9;
        bf16x8 af = *(const bf16x8*)&pa[cb];
        bf16x8 bfr[4];
#pragma unroll
        for (int ot = 0; ot < 4; ++ot) bfr[ot] = *(const bf16x8*)&pbm[(ot << 16) + cb];
#pragma unroll
        for (int ot = 0; ot < 4; ++ot)
            acc[ot] = __builtin_amdgcn_mfma_f32_16x16x32_bf16(af, bfr[ot], acc[ot], 0, 0, 0);
    }
    float* dst = xrp + ((size_t)((ks << 1) + b) << 18);
#pragma unroll
    for (int ot = 0; ot < 4; ++ot)
#pragma unroll
        for (int r = 0; r < 4; ++r) {
            int m = (mt << 4) + (quad << 2) + r;
            int o = (w << 6) + (ot << 4) + ln;
            dst[m * 256 + o] = acc[ot][r];
        }
}

// ---------------------------------------------------------------------------
// k_comb2: xrb[b][m][c] = bf16(BN(sum_ks xrp)).  grid = 512.
__global__ __launch_bounds__(256) void k_comb2(const float* __restrict__ xrp,
                                               const float* __restrict__ sg,
                                               const float* __restrict__ sb,
                                               const float* __restrict__ smn,
                                               const float* __restrict__ svar,
                                               __bf16* __restrict__ xrb) {
    int t = threadIdx.x, bid = blockIdx.x;
    int b = bid >> 8, m = ((bid & 255) << 2) + (t >> 6);
    int o4 = (t & 63) << 2;
    size_t base = (((size_t)b << 10) + m) << 8;
    float4 s0 = *(const float4*)&xrp[base + o4];
    float4 s1 = *(const float4*)&xrp[524288 + base + o4];
    float4 s2 = *(const float4*)&xrp[1048576 + base + o4];
    float4 s3 = *(const float4*)&xrp[1572864 + base + o4];
    float4 g = *(const float4*)&sg[o4];
    float4 vr = *(const float4*)&svar[o4];
    float4 mn = *(const float4*)&smn[o4];
    float4 bt = *(const float4*)&sb[o4];
    bf16x4 r;
    r[0] = (__bf16)((s0.x + s1.x + s2.x + s3.x - mn.x) * (g.x / sqrtf(vr.x + EPSF)) + bt.x);
    r[1] = (__bf16)((s0.y + s1.y + s2.y + s3.y - mn.y) * (g.y / sqrtf(vr.y + EPSF)) + bt.y);
    r[2] = (__bf16)((s0.z + s1.z + s2.z + s3.z - mn.z) * (g.z / sqrtf(vr.z + EPSF)) + bt.z);
    r[3] = (__bf16)((s0.w + s1.w + s2.w + s3.w - mn.w) * (g.w / sqrtf(vr.w + EPSF)) + bt.w);
    *(bf16x4*)&xrb[base + o4] = r;
}

// ---------------------------------------------------------------------------
// k_kmat2: MFMA GEMM kkbh = xrb x wkb, m=16/block.  grid = 128.
__global__ __launch_bounds__(256) void k_kmat2(const __bf16* __restrict__ xrb,
                                               const __bf16* __restrict__ wkb,
                                               __bf16* __restrict__ kkbh) {
    const int t = threadIdx.x, bid = blockIdx.x;
    const int b = bid >> 6, mt = bid & 63;
    const int w = t >> 6, lane = t & 63, ln = lane & 15, quad = lane >> 4;
    f32x4 acc[4];
#pragma unroll
    for (int ot = 0; ot < 4; ++ot) acc[ot] = (f32x4){0.f, 0.f, 0.f, 0.f};
    const __bf16* pa = xrb + ((((size_t)b << 10) + (mt << 4) + ln) << 8) + (quad << 3);
    const __bf16* pbm = wkb + (((w << 6) + ln) << 8) + (quad << 3);
#pragma unroll
    for (int cc = 0; cc < 8; ++cc) {
        const int cb = cc << 5;
        bf16x8 af = *(const bf16x8*)&pa[cb];
        bf16x8 bfr[4];
#pragma unroll
        for (int ot = 0; ot < 4; ++ot) bfr[ot] = *(const bf16x8*)&pbm[(ot << 12) + cb];
#pragma unroll
        for (int ot = 0; ot < 4; ++ot)
            acc[ot] = __builtin_amdgcn_mfma_f32_16x16x32_bf16(af, bfr[ot], acc[ot], 0, 0, 0);
    }
#pragma unroll
    for (int ot = 0; ot < 4; ++ot)
#pragma unroll
        for (int r = 0; r < 4; ++r) {
            int m = (mt << 4) + (quad << 2) + r;
            int h = (w << 1) + (ot >> 1);
            int d = ((ot & 1) << 4) + ln;
            kkbh[(((size_t)(b * 8 + h)) << 15) + (m << 5) + d] = (__bf16)acc[ot][r];
        }
}

// ---------------------------------------------------------------------------
// k_xt: x fp32 [b][c][n] -> xTf fragment-major.  grid = 512 (64 n / block).
__global__ __launch_bounds__(256) void k_xt(const float* __restrict__ x,
                                            __bf16* __restrict__ xTf) {
    __shared__ float ts[32 * 68];
    int t = threadIdx.x, bid = blockIdx.x;
    int b = bid >> 8, n0 = (bid & 255) << 6;
    const int nl = t >> 2;            // 0..63
    const int ch = (t & 3) << 3;      // c-offset 0,8,16,24
    const int n = n0 + nl;
    const int ntile = n >> 4, ln = n & 15, quad = ch >> 3;
    const int cl = t >> 3;            // load row 0..31
    const int n8 = (t & 7) << 3;      // load n-offset
    for (int s8 = 0; s8 < 8; ++s8) {
        int c0 = s8 << 5;
        __syncthreads();
        {
            const float* src = &x[((size_t)(b * 256 + c0 + cl) << 14) + n0 + n8];
            *(float4*)&ts[cl * 68 + n8] = *(const float4*)&src[0];
            *(float4*)&ts[cl * 68 + n8 + 4] = *(const float4*)&src[4];
        }
        __syncthreads();
        bf16x8 p;
#pragma unroll
        for (int j = 0; j < 8; ++j) p[j] = (__bf16)ts[(ch + j) * 68 + nl];
        *(bf16x8*)&xTf[(((((size_t)(b * 1024 + ntile) << 3) + s8) << 6) +
                        (quad << 4) + ln) << 3] = p;
    }
}

// ---------------------------------------------------------------------------
// k_scores2: MFMA q-GEMM + MFMA scores with per-head register-batched k-frags,
// single barrier for cross-wave max, rank-1 epilogue.  grid = 512.
__global__ __launch_bounds__(256) void k_scores2(const __bf16* __restrict__ xTf,
                                                 const __bf16* __restrict__ wqf,
                                                 const __bf16* __restrict__ kkbh,
                                                 const float* __restrict__ A,
                                                 const float* __restrict__ B0,
                                                 float* __restrict__ out) {
    __shared__ __align__(16) __bf16 qs[64 * 264];
    __shared__ float smax[2048];   // [w][h][n] = [4][8][64]
    __shared__ float ss[64];
    __shared__ float sA[256], sB[256];
    const int t = threadIdx.x;
    const int w = t >> 6;
    const int lane = t & 63;
    const int ln = lane & 15;
    const int quad = lane >> 4;
    const int b = blockIdx.x >> 8;
    const int n0 = (blockIdx.x & 255) << 6;

    // ---------------- q phase: q[64n][256o], wave w owns o in [w*64, w*64+64)
    f32x4 acc[4][4];
#pragma unroll
    for (int nt = 0; nt < 4; ++nt)
#pragma unroll
        for (int ot = 0; ot < 4; ++ot) acc[nt][ot] = (f32x4){0.f, 0.f, 0.f, 0.f};
    const __bf16* pa = xTf + (((size_t)(b * 1024 + (n0 >> 4))) << 12) + (lane << 3);
    const __bf16* pbm = wqf + ((size_t)w << 14) + (lane << 3);
#pragma unroll 2
    for (int cc = 0; cc < 8; ++cc) {
        const int cb = cc << 9;
        bf16x8 af[4], bfr[4];
#pragma unroll
        for (int nt = 0; nt < 4; ++nt) af[nt] = *(const bf16x8*)&pa[(nt << 12) + cb];
#pragma unroll
        for (int ot = 0; ot < 4; ++ot) bfr[ot] = *(const bf16x8*)&pbm[(ot << 12) + cb];
#pragma unroll
        for (int nt = 0; nt < 4; ++nt)
#pragma unroll
            for (int ot = 0; ot < 4; ++ot)
                acc[nt][ot] = __builtin_amdgcn_mfma_f32_16x16x32_bf16(af[nt], bfr[ot],
                                                                      acc[nt][ot], 0, 0, 0);
    }
#pragma unroll
    for (int nt = 0; nt < 4; ++nt)
#pragma unroll
        for (int ot = 0; ot < 4; ++ot)
#pragma unroll
            for (int r = 0; r < 4; ++r)
                qs[((nt << 4) + (quad << 2) + r) * 264 + (w << 6) + (ot << 4) + ln] =
                    (__bf16)acc[nt][ot][r];
    __syncthreads();

    // ---------------- score phase: per head, batch-preload 16 k-frags
    const f32x4 zf = {0.f, 0.f, 0.f, 0.f};
    for (int h = 0; h < 8; ++h) {
        bf16x8 qb[4];
#pragma unroll
        for (int nt = 0; nt < 4; ++nt)
            qb[nt] = *(const bf16x8*)&qs[((nt << 4) + ln) * 264 + (h << 5) + (quad << 3)];
        const __bf16* kb_base = kkbh + ((size_t)(b * 8 + h) << 15) + (ln << 5) + (quad << 3);
        bf16x8 kb[16];
#pragma unroll
        for (int i = 0; i < 16; ++i)
            kb[i] = *(const bf16x8*)&kb_base[((w << 8) + (i << 4)) << 5];
        float rmx[4] = {-INFINITY, -INFINITY, -INFINITY, -INFINITY};
#pragma unroll
        for (int i = 0; i < 16; ++i)
#pragma unroll
            for (int nt = 0; nt < 4; ++nt) {
                f32x4 d = __builtin_amdgcn_mfma_f32_16x16x32_bf16(kb[i], qb[nt], zf, 0, 0, 0);
                rmx[nt] = fmaxf(rmx[nt], fmaxf(fmaxf(d[0], d[1]), fmaxf(d[2], d[3])));
            }
#pragma unroll
        for (int nt = 0; nt < 4; ++nt) {
            rmx[nt] = fmaxf(rmx[nt], __shfl_xor(rmx[nt], 16, 64));
            rmx[nt] = fmaxf(rmx[nt], __shfl_xor(rmx[nt], 32, 64));
        }
        if (lane < 16) {
#pragma unroll
            for (int nt = 0; nt < 4; ++nt)
                smax[(w << 9) + (h << 6) + (nt << 4) + lane] = rmx[nt];
        }
    }
    __syncthreads();
    if (t < 64) {
        float ssum = 0.f;
#pragma unroll
        for (int h = 0; h < 8; ++h) {
            float vv = fmaxf(fmaxf(smax[(h << 6) + t], smax[512 + (h << 6) + t]),
                             fmaxf(smax[1024 + (h << 6) + t], smax[1536 + (h << 6) + t]));
            ssum += vv;
        }
        ss[t] = ssum;
    }
    sA[t] = A[b * 256 + t];
    sB[t] = B0[t];
    __syncthreads();

    // ---------------- epilogue: out[b][c][n0..n0+63] = A*s + B0
#pragma unroll
    for (int i = 0; i < 16; ++i) {
        int e = t + (i << 8);
        int c = e >> 4, n4 = (e & 15) << 2;
        float4 s4 = *(const float4*)&ss[n4];
        float a = sA[c], bb = sB[c];
        float4 o4 = make_float4(fmaf(a, s4.x, bb), fmaf(a, s4.y, bb),
                                fmaf(a, s4.z, bb), fmaf(a, s4.w, bb));
        *(float4*)&out[((size_t)(b * 256 + c) << 14) + n0 + n4] = o4;
    }
}

// ---------------------------------------------------------------------------
extern "C" void kernel_launch(void* const* d_in, const int* in_sizes, int n_in,
                              void* d_out, int out_size, void* d_ws, size_t ws_size,
                              hipStream_t stream) {
    const float* x    = (const float*)d_in[0];
    const float* wq   = (const float*)d_in[1];
    const float* wk   = (const float*)d_in[2];
    const float* wsr  = (const float*)d_in[3];
    const float* sg   = (const float*)d_in[4];
    const float* sb   = (const float*)d_in[5];
    const float* smn  = (const float*)d_in[6];
    const float* svr  = (const float*)d_in[7];
    const float* wproj= (const float*)d_in[8];
    const float* pg   = (const float*)d_in[9];
    const float* pb   = (const float*)d_in[10];
    const float* pm   = (const float*)d_in[11];
    const float* pvr  = (const float*)d_in[12];
    float* out = (float*)d_out;

    char* W = (char*)d_ws;
    float*  w_v   = (float*) (W + 0);          // 512 f (sum accumulators)
    float*  w_A   = (float*) (W + 4096);       // 512 f
    float*  w_B0  = (float*) (W + 8192);       // 256 f
    __bf16* w_wqf = (__bf16*)(W + 16384);      // 128 KB  (frag-major)
    __bf16* w_wkb = (__bf16*)(W + 147456);     // 128 KB  (flat, *SCALE)
    __bf16* w_wsrf= (__bf16*)(W + 278528);     // 2 MB    (frag-major)
    __bf16* w_xrb = (__bf16*)(W + 2375680);    // 512 KB  ([b][m][c])
    __bf16* w_kkbh= (__bf16*)(W + 2899968);    // 1 MB    ([b][h][m][d])
    float*  w_xrp = (float*) (W + 3948544);    // 8 MB    (split-K partials)
    __bf16* w_Pbf = (__bf16*)(W + 12337152);   // 16 MB   (frag-major)
    __bf16* w_xTf = (__bf16*)(W + 12337152);   // 16 MB   — alias (Pbf dead by k_xt)

    k_wprep<<<576, 256, 0, stream>>>(wq, wk, wsr, w_wqf, w_wkb, w_wsrf, w_v);
    k_im2col<<<512, 256, 0, stream>>>(x, w_Pbf, w_v);
    k_ab<<<2, 256, 0, stream>>>(w_v, wproj, pg, pb, pm, pvr, w_A, w_B0);
    k_conv1<<<512, 256, 0, stream>>>(w_Pbf, w_wsrf, w_xrp);
    k_comb2<<<512, 256, 0, stream>>>(w_xrp, sg, sb, smn, svr, w_xrb);
    k_kmat2<<<128, 256, 0, stream>>>(w_xrb, w_wkb, w_kkbh);
    k_xt<<<512, 256, 0, stream>>>(x, w_xTf);   // clobbers Pbf (dead)
    k_scores2<<<512, 256, 0, stream>>>(w_xTf, w_wqf, w_kkbh, w_A, w_B0, out);
}

// Round 7
// 191.444 us; speedup vs baseline: 3.7866x; 1.0174x over previous
//
#include <hip/hip_runtime.h>
#include <hip/hip_bf16.h>
#include <math.h>

// Problem constants (B=2, C=256, H=W=128, N=16384, SR=4, HEADS=8, hd=32, M=1024)
#define EPSF 1e-5f
#define SCALE 0.17677669529663687f  // 1/sqrt(32)

typedef __bf16 bf16x8 __attribute__((ext_vector_type(8)));
typedef __bf16 bf16x4 __attribute__((ext_vector_type(4)));
typedef float f32x4 __attribute__((ext_vector_type(4)));

// Fragment-major layouts (MFMA 16x16x32, A/B frag = [row/col ln<16][k=quad*8+j]):
//   xTf : x^T  [b][n_tile(1024)][cc(8)][lane(64)][j(8)]
//   wqf : w_q  [o_tile(16)][cc(8)][lane][j]
//   Pbf : P    [b][m_tile(64)][cc(128)][lane][j]
//   wsrf: w_sr [o_tile(16)][cc(128)][lane][j]
//   kkbh: k    [b][h(8)][m(1024)][d(32)]

// ---------------------------------------------------------------------------
// k_wprep: weight conversions + v/ssg zeroing.  608 blocks.
__global__ __launch_bounds__(256) void k_wprep(const float* __restrict__ wq,
                                               const float* __restrict__ wk,
                                               const float* __restrict__ wsr,
                                               __bf16* __restrict__ wqf,
                                               __bf16* __restrict__ wkb,
                                               __bf16* __restrict__ wsrf,
                                               float* __restrict__ v,
                                               float* __restrict__ ssg) {
    int bi = blockIdx.x, t = threadIdx.x;
    if (bi >= 576) {  // zero ssg (2*16384 floats)
        int e = (bi - 576) * 256 + t;
        *(float4*)&ssg[e << 2] = make_float4(0.f, 0.f, 0.f, 0.f);
        return;
    }
    if (bi < 32) {
        if (bi == 0) { v[t] = 0.f; v[256 + t] = 0.f; }
        int tt = bi * 256 + t;
        int o = tt >> 5, chunk = tt & 31;
        float4 v0 = *(const float4*)&wq[o * 256 + (chunk << 3)];
        float4 v1 = *(const float4*)&wq[o * 256 + (chunk << 3) + 4];
        bf16x8 p;
        p[0] = (__bf16)v0.x; p[1] = (__bf16)v0.y; p[2] = (__bf16)v0.z; p[3] = (__bf16)v0.w;
        p[4] = (__bf16)v1.x; p[5] = (__bf16)v1.y; p[6] = (__bf16)v1.z; p[7] = (__bf16)v1.w;
        int cc = chunk >> 2, quad = chunk & 3;
        *(bf16x8*)&wqf[(((((o >> 4) << 3) + cc) << 6) + (quad << 4) + (o & 15)) << 3] = p;
    } else if (bi < 64) {
        int e = (bi - 32) * 256 + t;
        float4 v0 = *(const float4*)&wk[e << 3];
        float4 v1 = *(const float4*)&wk[(e << 3) + 4];
        bf16x8 p;
        p[0] = (__bf16)(v0.x * SCALE); p[1] = (__bf16)(v0.y * SCALE);
        p[2] = (__bf16)(v0.z * SCALE); p[3] = (__bf16)(v0.w * SCALE);
        p[4] = (__bf16)(v1.x * SCALE); p[5] = (__bf16)(v1.y * SCALE);
        p[6] = (__bf16)(v1.z * SCALE); p[7] = (__bf16)(v1.w * SCALE);
        *(bf16x8*)&wkb[e << 3] = p;
    } else {
        int tt = (bi - 64) * 256 + t;
        int o = tt >> 9, chunk = tt & 511;
        float4 v0 = *(const float4*)&wsr[o * 4096 + (chunk << 3)];
        float4 v1 = *(const float4*)&wsr[o * 4096 + (chunk << 3) + 4];
        bf16x8 p;
        p[0] = (__bf16)v0.x; p[1] = (__bf16)v0.y; p[2] = (__bf16)v0.z; p[3] = (__bf16)v0.w;
        p[4] = (__bf16)v1.x; p[5] = (__bf16)v1.y; p[6] = (__bf16)v1.z; p[7] = (__bf16)v1.w;
        int cc = chunk >> 2, quad = chunk & 3;
        *(bf16x8*)&wsrf[(((((o >> 4) << 7) + cc) << 6) + (quad << 4) + (o & 15)) << 3] = p;
    }
}

// ---------------------------------------------------------------------------
// k_stage: blocks 0..511 = im2col (+v atomics); 512..1023 = xT transpose.
__global__ __launch_bounds__(256) void k_stage(const float* __restrict__ x,
                                               __bf16* __restrict__ Pbf,
                                               __bf16* __restrict__ xTf,
                                               float* __restrict__ v) {
    int t = threadIdx.x, bid0 = blockIdx.x;
    if (bid0 < 512) {
        // ---- im2col ----
        __shared__ float csum[32];
        int bid = bid0;
        int b = bid >> 8, hm = (bid >> 3) & 31, ccg = bid & 7;
        int wm = t >> 3, c8 = t & 7;
        if (t < 32) csum[t] = 0.f;
        __syncthreads();
        const int mtile = (hm << 1) + (wm >> 4);
        const int ln = wm & 15;
#pragma unroll
        for (int cci = 0; cci < 4; ++cci) {
            int c = (ccg << 5) + (cci << 3) + c8;
            const float* src = x + ((size_t)(b * 256 + c) << 14) + (hm << 9) + (wm << 2);
            bf16x8 o0, o1;
            float s = 0.f;
#pragma unroll
            for (int p = 0; p < 2; ++p) {
                float4 vv = *(const float4*)&src[p << 7];
                s += vv.x + vv.y + vv.z + vv.w;
                o0[p * 4 + 0] = (__bf16)vv.x; o0[p * 4 + 1] = (__bf16)vv.y;
                o0[p * 4 + 2] = (__bf16)vv.z; o0[p * 4 + 3] = (__bf16)vv.w;
            }
#pragma unroll
            for (int p = 0; p < 2; ++p) {
                float4 vv = *(const float4*)&src[(p + 2) << 7];
                s += vv.x + vv.y + vv.z + vv.w;
                o1[p * 4 + 0] = (__bf16)vv.x; o1[p * 4 + 1] = (__bf16)vv.y;
                o1[p * 4 + 2] = (__bf16)vv.z; o1[p * 4 + 3] = (__bf16)vv.w;
            }
            size_t d0 = (((((size_t)(b * 64 + mtile) << 7) + (c >> 1)) << 6) +
                         (((c & 1) << 1) << 4) + ln) << 3;
            *(bf16x8*)&Pbf[d0] = o0;
            *(bf16x8*)&Pbf[d0 + 128] = o1;
            atomicAdd(&csum[(cci << 3) + c8], s);
        }
        __syncthreads();
        if (t < 32) atomicAdd(&v[b * 256 + (ccg << 5) + t], csum[t]);
    } else {
        // ---- xT ----
        __shared__ float ts[32 * 68];
        int bid = bid0 - 512;
        int b = bid >> 8, n0 = (bid & 255) << 6;
        const int nl = t >> 2;
        const int ch = (t & 3) << 3;
        const int n = n0 + nl;
        const int ntile = n >> 4, ln = n & 15, quad = ch >> 3;
        const int cl = t >> 3;
        const int n8 = (t & 7) << 3;
        for (int s8 = 0; s8 < 8; ++s8) {
            int c0 = s8 << 5;
            __syncthreads();
            {
                const float* src = &x[((size_t)(b * 256 + c0 + cl) << 14) + n0 + n8];
                *(float4*)&ts[cl * 68 + n8] = *(const float4*)&src[0];
                *(float4*)&ts[cl * 68 + n8 + 4] = *(const float4*)&src[4];
            }
            __syncthreads();
            bf16x8 p;
#pragma unroll
            for (int j = 0; j < 8; ++j) p[j] = (__bf16)ts[(ch + j) * 68 + nl];
            *(bf16x8*)&xTf[(((((size_t)(b * 1024 + ntile) << 3) + s8) << 6) +
                            (quad << 4) + ln) << 3] = p;
        }
    }
}

// ---------------------------------------------------------------------------
// k_conv1f: full-K MFMA GEMM + fused BN + bf16 store.  No split-K, no partials.
// grid = b(2) * mt(64) * og(4) = 512; wave w handles otile og*4+w.
__global__ __launch_bounds__(256) void k_conv1f(const __bf16* __restrict__ Pbf,
                                                const __bf16* __restrict__ wsrf,
                                                const float* __restrict__ sg,
                                                const float* __restrict__ sb,
                                                const float* __restrict__ smn,
                                                const float* __restrict__ svar,
                                                __bf16* __restrict__ xrb) {
    const int t = threadIdx.x, bid = blockIdx.x;
    const int b = bid & 1, mt = (bid >> 1) & 63, og = bid >> 7;
    const int w = t >> 6, lane = t & 63, ln = lane & 15, quad = lane >> 4;
    f32x4 acc = (f32x4){0.f, 0.f, 0.f, 0.f};
    const __bf16* pa = Pbf + ((size_t)(b * 64 + mt) << 16) + (lane << 3);
    const __bf16* pbm = wsrf + ((size_t)(og * 4 + w) << 16) + (lane << 3);
#pragma unroll 8
    for (int cc = 0; cc < 128; ++cc) {
        bf16x8 af = *(const bf16x8*)&pa[cc << 9];
        bf16x8 bf = *(const bf16x8*)&pbm[cc << 9];
        acc = __builtin_amdgcn_mfma_f32_16x16x32_bf16(af, bf, acc, 0, 0, 0);
    }
    const int o = (og << 6) + (w << 4) + ln;
    float inv = sg[o] / sqrtf(svar[o] + EPSF);
    float mn = smn[o], bt = sb[o];
#pragma unroll
    for (int r = 0; r < 4; ++r) {
        int m = (mt << 4) + (quad << 2) + r;
        xrb[(((size_t)b << 10) + m) * 256 + o] = (__bf16)((acc[r] - mn) * inv + bt);
    }
}

// ---------------------------------------------------------------------------
// k_kmat2: MFMA GEMM kkbh = xrb x wkb (blocks 0..127) + k_ab work (128..129).
__global__ __launch_bounds__(256) void k_kmat2(const __bf16* __restrict__ xrb,
                                               const __bf16* __restrict__ wkb,
                                               __bf16* __restrict__ kkbh,
                                               const float* __restrict__ v,
                                               const float* __restrict__ wproj,
                                               const float* __restrict__ pg,
                                               const float* __restrict__ pb,
                                               const float* __restrict__ pm,
                                               const float* __restrict__ pvar,
                                               float* __restrict__ A,
                                               float* __restrict__ B0) {
    const int t = threadIdx.x, bid = blockIdx.x;
    if (bid >= 128) {
        // ---- k_ab ----
        __shared__ float vl[256];
        int b = bid - 128;
        vl[t] = v[b * 256 + t] * (1.0f / 16384.0f);
        __syncthreads();
        const float* wr = wproj + t * 256;
        float s = 0.f;
#pragma unroll 8
        for (int c = 0; c < 256; c += 4) {
            float4 w4 = *(const float4*)&wr[c];
            s += w4.x * vl[c] + w4.y * vl[c + 1] + w4.z * vl[c + 2] + w4.w * vl[c + 3];
        }
        float inv = pg[t] / sqrtf(pvar[t] + EPSF);
        A[b * 256 + t] = s * inv;
        if (b == 0) B0[t] = pb[t] - pm[t] * inv;
        return;
    }
    const int b = bid >> 6, mt = bid & 63;
    const int w = t >> 6, lane = t & 63, ln = lane & 15, quad = lane >> 4;
    f32x4 acc[4];
#pragma unroll
    for (int ot = 0; ot < 4; ++ot) acc[ot] = (f32x4){0.f, 0.f, 0.f, 0.f};
    const __bf16* pa = xrb + ((((size_t)b << 10) + (mt << 4) + ln) << 8) + (quad << 3);
    const __bf16* pbm = wkb + (((w << 6) + ln) << 8) + (quad << 3);
#pragma unroll
    for (int cc = 0; cc < 8; ++cc) {
        const int cb = cc << 5;
        bf16x8 af = *(const bf16x8*)&pa[cb];
        bf16x8 bfr[4];
#pragma unroll
        for (int ot = 0; ot < 4; ++ot) bfr[ot] = *(const bf16x8*)&pbm[(ot << 12) + cb];
#pragma unroll
        for (int ot = 0; ot < 4; ++ot)
            acc[ot] = __builtin_amdgcn_mfma_f32_16x16x32_bf16(af, bfr[ot], acc[ot], 0, 0, 0);
    }
#pragma unroll
    for (int ot = 0; ot < 4; ++ot)
#pragma unroll
        for (int r = 0; r < 4; ++r) {
            int m = (mt << 4) + (quad << 2) + r;
            int h = (w << 1) + (ot >> 1);
            int d = ((ot & 1) << 4) + ln;
            kkbh[(((size_t)(b * 8 + h)) << 15) + (m << 5) + d] = (__bf16)acc[ot][r];
        }
}

// ---------------------------------------------------------------------------
// k_scores2: head-pair split.  grid = b(2) x nchunk(256) x hp(4) = 2048.
// q phase: wave w = ntile w, 64 o (the pair's heads).  score phase: wave w =
// m-quarter.  Result: atomicAdd of (max_h0 + max_h1) into ssg[b][n].
__global__ __launch_bounds__(256) void k_scores2(const __bf16* __restrict__ xTf,
                                                 const __bf16* __restrict__ wqf,
                                                 const __bf16* __restrict__ kkbh,
                                                 float* __restrict__ ssg) {
    __shared__ __align__(16) __bf16 qs[64 * 72];
    __shared__ float smax[512];  // [w][hl][n64]
    const int t = threadIdx.x;
    const int w = t >> 6;
    const int lane = t & 63;
    const int ln = lane & 15;
    const int quad = lane >> 4;
    const int bx = blockIdx.x;
    const int hp = bx & 3;
    const int n0 = ((bx >> 2) & 255) << 6;
    const int b = bx >> 10;

    // ---------------- q phase: wave w computes q[ntile w][64 o of pair]
    f32x4 acc[4];
#pragma unroll
    for (int ot = 0; ot < 4; ++ot) acc[ot] = (f32x4){0.f, 0.f, 0.f, 0.f};
    const __bf16* pa = xTf + ((size_t)(b * 1024 + (n0 >> 4) + w) << 12) + (lane << 3);
    const __bf16* pbm = wqf + ((size_t)(hp << 2) << 12) + (lane << 3);
#pragma unroll 2
    for (int cc = 0; cc < 8; ++cc) {
        const int cb = cc << 9;
        bf16x8 af = *(const bf16x8*)&pa[cb];
        bf16x8 bfr[4];
#pragma unroll
        for (int ot = 0; ot < 4; ++ot) bfr[ot] = *(const bf16x8*)&pbm[(ot << 12) + cb];
#pragma unroll
        for (int ot = 0; ot < 4; ++ot)
            acc[ot] = __builtin_amdgcn_mfma_f32_16x16x32_bf16(af, bfr[ot], acc[ot], 0, 0, 0);
    }
#pragma unroll
    for (int ot = 0; ot < 4; ++ot)
#pragma unroll
        for (int r = 0; r < 4; ++r)
            qs[((w << 4) + (quad << 2) + r) * 72 + (ot << 4) + ln] = (__bf16)acc[ot][r];
    __syncthreads();

    // ---------------- score phase: wave w = m range [w*256, w*256+256)
    const f32x4 zf = {0.f, 0.f, 0.f, 0.f};
#pragma unroll
    for (int hl = 0; hl < 2; ++hl) {
        const int h = (hp << 1) + hl;
        bf16x8 qb[4];
#pragma unroll
        for (int nt = 0; nt < 4; ++nt)
            qb[nt] = *(const bf16x8*)&qs[((nt << 4) + ln) * 72 + (hl << 5) + (quad << 3)];
        const __bf16* kb_base = kkbh + ((size_t)(b * 8 + h) << 15) + (ln << 5) + (quad << 3);
        bf16x8 kb[16];
#pragma unroll
        for (int i = 0; i < 16; ++i)
            kb[i] = *(const bf16x8*)&kb_base[((w << 8) + (i << 4)) << 5];
        float rmx[4] = {-INFINITY, -INFINITY, -INFINITY, -INFINITY};
#pragma unroll
        for (int i = 0; i < 16; ++i)
#pragma unroll
            for (int nt = 0; nt < 4; ++nt) {
                f32x4 d = __builtin_amdgcn_mfma_f32_16x16x32_bf16(kb[i], qb[nt], zf, 0, 0, 0);
                float t1 = fmaxf(fmaxf(d[0], d[1]), d[2]);       // -> v_max3
                rmx[nt] = fmaxf(fmaxf(t1, d[3]), rmx[nt]);       // -> v_max3
            }
#pragma unroll
        for (int nt = 0; nt < 4; ++nt) {
            rmx[nt] = fmaxf(rmx[nt], __shfl_xor(rmx[nt], 16, 64));
            rmx[nt] = fmaxf(rmx[nt], __shfl_xor(rmx[nt], 32, 64));
        }
        if (lane < 16) {
#pragma unroll
            for (int nt = 0; nt < 4; ++nt)
                smax[(w << 7) + (hl << 6) + (nt << 4) + lane] = rmx[nt];
        }
    }
    __syncthreads();
    if (t < 64) {
        float s0 = fmaxf(fmaxf(smax[t], smax[128 + t]), fmaxf(smax[256 + t], smax[384 + t]));
        float s1 = fmaxf(fmaxf(smax[64 + t], smax[192 + t]),
                         fmaxf(smax[320 + t], smax[448 + t]));
        atomicAdd(&ssg[(b << 14) + n0 + t], s0 + s1);
    }
}

// ---------------------------------------------------------------------------
// k_epi: out[b][c][n] = A[b][c]*ssg[b][n] + B0[c].  grid = 512.
__global__ __launch_bounds__(256) void k_epi(const float* __restrict__ ssg,
                                             const float* __restrict__ A,
                                             const float* __restrict__ B0,
                                             float* __restrict__ out) {
    __shared__ float ss[64], sA[256], sB[256];
    const int t = threadIdx.x, bid = blockIdx.x;
    const int b = bid >> 8, n0 = (bid & 255) << 6;
    if (t < 64) ss[t] = ssg[(b << 14) + n0 + t];
    sA[t] = A[b * 256 + t];
    sB[t] = B0[t];
    __syncthreads();
#pragma unroll
    for (int i = 0; i < 16; ++i) {
        int e = t + (i << 8);
        int c = e >> 4, n4 = (e & 15) << 2;
        float4 s4 = *(const float4*)&ss[n4];
        float a = sA[c], bb = sB[c];
        float4 o4 = make_float4(fmaf(a, s4.x, bb), fmaf(a, s4.y, bb),
                                fmaf(a, s4.z, bb), fmaf(a, s4.w, bb));
        *(float4*)&out[((size_t)(b * 256 + c) << 14) + n0 + n4] = o4;
    }
}

// ---------------------------------------------------------------------------
extern "C" void kernel_launch(void* const* d_in, const int* in_sizes, int n_in,
                              void* d_out, int out_size, void* d_ws, size_t ws_size,
                              hipStream_t stream) {
    const float* x    = (const float*)d_in[0];
    const float* wq   = (const float*)d_in[1];
    const float* wk   = (const float*)d_in[2];
    const float* wsr  = (const float*)d_in[3];
    const float* sg   = (const float*)d_in[4];
    const float* sb   = (const float*)d_in[5];
    const float* smn  = (const float*)d_in[6];
    const float* svr  = (const float*)d_in[7];
    const float* wproj= (const float*)d_in[8];
    const float* pg   = (const float*)d_in[9];
    const float* pb   = (const float*)d_in[10];
    const float* pm   = (const float*)d_in[11];
    const float* pvr  = (const float*)d_in[12];
    float* out = (float*)d_out;

    char* W = (char*)d_ws;
    float*  w_v   = (float*) (W + 0);          // 512 f
    float*  w_A   = (float*) (W + 4096);       // 512 f
    float*  w_B0  = (float*) (W + 8192);       // 256 f
    float*  w_ssg = (float*) (W + 12288);      // 128 KB (2*16384 f)
    __bf16* w_wqf = (__bf16*)(W + 147456);     // 128 KB
    __bf16* w_wkb = (__bf16*)(W + 278528);     // 128 KB
    __bf16* w_wsrf= (__bf16*)(W + 409600);     // 2 MB
    __bf16* w_xrb = (__bf16*)(W + 2506752);    // 512 KB
    __bf16* w_kkbh= (__bf16*)(W + 3031040);    // 1 MB
    __bf16* w_Pbf = (__bf16*)(W + 4079616);    // 16.8 MB
    __bf16* w_xTf = (__bf16*)(W + 20856832);   // 16.8 MB

    k_wprep<<<608, 256, 0, stream>>>(wq, wk, wsr, w_wqf, w_wkb, w_wsrf, w_v, w_ssg);
    k_stage<<<1024, 256, 0, stream>>>(x, w_Pbf, w_xTf, w_v);
    k_conv1f<<<512, 256, 0, stream>>>(w_Pbf, w_wsrf, sg, sb, smn, svr, w_xrb);
    k_kmat2<<<130, 256, 0, stream>>>(w_xrb, w_wkb, w_kkbh, w_v, wproj, pg, pb, pm, pvr,
                                     w_A, w_B0);
    k_scores2<<<2048, 256, 0, stream>>>(w_xTf, w_wqf, w_kkbh, w_ssg);
    k_epi<<<512, 256, 0, stream>>>(w_ssg, w_A, w_B0, out);
}